// Round 9
// baseline (241.602 us; speedup 1.0000x reference)
//
#include <hip/hip_runtime.h>

typedef unsigned short u16;
typedef __bf16 bf16x8 __attribute__((ext_vector_type(8)));
typedef float f32x4 __attribute__((ext_vector_type(4)));
typedef u16 u16x8 __attribute__((ext_vector_type(8)));
typedef u16 u16x4 __attribute__((ext_vector_type(4)));

#define NUM_HEADS 16
#define HIDDEN 1024
#define BATCH 4
#define SEQ 1024
// 0.125 * log2(e): fold the 1/sqrt(64) scale and the exp->exp2 conversion
#define C1 0.1803368809109783f
#define LOG2E 1.4426950408889634f

#define VMCNT0 asm volatile("s_waitcnt vmcnt(0)" ::: "memory")

static __device__ __forceinline__ u16 f2bf(float x) {
  unsigned u = __float_as_uint(x);
  u = u + 0x7FFFu + ((u >> 16) & 1u);
  return (u16)(u >> 16);
}
static __device__ __forceinline__ float bf2f(u16 b) {
  return __uint_as_float(((unsigned)b) << 16);
}
static __device__ __forceinline__ void async16(u16* lds, const u16* g) {
  __builtin_amdgcn_global_load_lds(
      (const __attribute__((address_space(1))) void*)g,
      (__attribute__((address_space(3))) void*)lds, 16, 0, 0);
}
static __device__ __forceinline__ void ntstore4(float* p, f32x4 v) {
  __builtin_nontemporal_store(v, (f32x4*)p);
}

// ---------------- merged prep: cvt x2 | wtrans | mask in one launch ----------------
__global__ __launch_bounds__(256) void k_prep(
    const float* __restrict__ from, u16* __restrict__ Af,
    const float* __restrict__ to, u16* __restrict__ At,
    const float* __restrict__ Wq, const float* __restrict__ Wk,
    const float* __restrict__ Wv, u16* __restrict__ Wt,
    const float* __restrict__ mask, u16* __restrict__ adder, int* __restrict__ flags) {
  int bid = blockIdx.x;
  int tid = threadIdx.x;
  if (bid < 4096) {
    const float* in = (bid < 2048) ? from : to;
    u16* out = (bid < 2048) ? Af : At;
    int i = (bid & 2047) * 256 + tid;
    float4 a = ((const float4*)in)[i * 2];
    float4 b = ((const float4*)in)[i * 2 + 1];
    u16x8 v;
    v[0] = f2bf(a.x); v[1] = f2bf(a.y); v[2] = f2bf(a.z); v[3] = f2bf(a.w);
    v[4] = f2bf(b.x); v[5] = f2bf(b.y); v[6] = f2bf(b.z); v[7] = f2bf(b.w);
    *(u16x8*)&out[(size_t)i * 8] = v;
  } else if (bid < 4864) {
    __shared__ float tile[64][65];
    int wid = bid - 4096;
    int z = wid >> 8, rem = wid & 255;
    int x = rem & 15, y = rem >> 4;
    const float* W = (z == 0) ? Wq : (z == 1) ? Wk : Wv;
    u16* out = Wt + (size_t)z * HIDDEN * HIDDEN;
    int k0 = y * 64, n0 = x * 64;
    int r = tid >> 6, c = tid & 63;
#pragma unroll
    for (int i = 0; i < 16; ++i)
      tile[i * 4 + r][c] = W[(size_t)(k0 + i * 4 + r) * HIDDEN + n0 + c];
    __syncthreads();
#pragma unroll
    for (int i = 0; i < 16; ++i)
      out[(size_t)(n0 + i * 4 + r) * HIDDEN + k0 + c] = f2bf(tile[c][i * 4 + r]);
  } else {
    int wid = bid - 4864;
    int tt = wid & 7, ft = (wid >> 3) & 7, b = wid >> 6;
    __shared__ int sflag;
    if (tid == 0) sflag = 0;
    __syncthreads();
    size_t base = ((size_t)b * SEQ + ft * 128) * SEQ + tt * 128;
    int any = 0;
#pragma unroll
    for (int i = 0; i < 16; ++i) {
      int idx = i * 256 + tid;
      int r = idx >> 5, c4 = idx & 31;
      float4 v = *(const float4*)&mask[base + (size_t)r * SEQ + c4 * 4];
      any |= (v.x != 1.0f) | (v.y != 1.0f) | (v.z != 1.0f) | (v.w != 1.0f);
    }
    if (any) sflag = 1;
    __syncthreads();
    if (sflag) {
#pragma unroll
      for (int i = 0; i < 16; ++i) {
        int idx = i * 256 + tid;
        int r = idx >> 5, c4 = idx & 31;
        float4 v = *(const float4*)&mask[base + (size_t)r * SEQ + c4 * 4];
        u16x4 o;
        o[0] = f2bf((1.0f - v.x) * -10000.0f * LOG2E);
        o[1] = f2bf((1.0f - v.y) * -10000.0f * LOG2E);
        o[2] = f2bf((1.0f - v.z) * -10000.0f * LOG2E);
        o[3] = f2bf((1.0f - v.w) * -10000.0f * LOG2E);
        *(u16x4*)&adder[base + (size_t)r * SEQ + c4 * 4] = o;
      }
    }
    if (tid == 0) flags[(b * 8 + ft) * 8 + tt] = sflag;
  }
}

// ---------------- QKV GEMM: 128x128 tile, BK=64, single-buffer ----------------
__global__ __launch_bounds__(256) void k_gemm(
    const u16* __restrict__ Af, const u16* __restrict__ At,
    const u16* __restrict__ Wt,
    const float* __restrict__ bq, const float* __restrict__ bk, const float* __restrict__ bv,
    u16* __restrict__ Qh, u16* __restrict__ Kh, u16* __restrict__ Vt) {
  __shared__ u16 sAB[2 * 128 * 64];
  u16* sA = sAB;
  u16* sB = sAB + 128 * 64;
  int which = blockIdx.z;
  const u16* A = (which == 0) ? Af : At;
  const u16* B = Wt + (size_t)which * HIDDEN * HIDDEN;
  const float* bias = (which == 0) ? bq : (which == 1) ? bk : bv;
  int wg = blockIdx.x + 8 * blockIdx.y;
  int xcd = wg & 7, j = wg >> 3;
  int ntile = j & 7, mstrip = xcd * 4 + (j >> 3);
  int m0 = mstrip * 128, n0 = ntile * 128;
  int tid = threadIdx.x, w = tid >> 6, lane = tid & 63;
  int wr = w >> 1, wc = w & 1;
  int g = lane >> 4, cc = lane & 15;

  f32x4 acc[4][4] = {};

  int sx[4], srow[4], scol[4];
#pragma unroll
  for (int i = 0; i < 4; ++i) {
    int ch = w * 4 + i;
    int x = ch * 1024 + lane * 16;
    int row = x >> 7;
    int colb = (x & 127) ^ ((row & 7) << 4);
    sx[i] = ch * 512;
    srow[i] = row;
    scol[i] = colb >> 1;
  }

  for (int kt = 0; kt < HIDDEN / 64; ++kt) {
    __syncthreads();
#pragma unroll
    for (int i = 0; i < 4; ++i) {
      async16(&sA[sx[i]], A + (size_t)(m0 + srow[i]) * HIDDEN + kt * 64 + scol[i]);
      async16(&sB[sx[i]], B + (size_t)(n0 + srow[i]) * HIDDEN + kt * 64 + scol[i]);
    }
    VMCNT0;
    __syncthreads();
#pragma unroll
    for (int kk = 0; kk < 2; ++kk) {
      bf16x8 af[4], bfr[4];
#pragma unroll
      for (int mf = 0; mf < 4; ++mf) {
        int row = wr * 64 + mf * 16 + cc;
        int colb = (kk * 64 + (g << 4)) ^ ((row & 7) << 4);
        af[mf] = *(const bf16x8*)&sA[(row * 128 + colb) >> 1];
      }
#pragma unroll
      for (int nf = 0; nf < 4; ++nf) {
        int row = wc * 64 + nf * 16 + cc;
        int colb = (kk * 64 + (g << 4)) ^ ((row & 7) << 4);
        bfr[nf] = *(const bf16x8*)&sB[(row * 128 + colb) >> 1];
      }
#pragma unroll
      for (int mf = 0; mf < 4; ++mf)
#pragma unroll
        for (int nf = 0; nf < 4; ++nf)
          acc[mf][nf] = __builtin_amdgcn_mfma_f32_16x16x32_bf16(af[mf], bfr[nf], acc[mf][nf], 0, 0, 0);
    }
  }

  if (which != 2) {
#pragma unroll
    for (int mf = 0; mf < 4; ++mf) {
#pragma unroll
      for (int nf = 0; nf < 4; ++nf) {
        int n = n0 + wc * 64 + nf * 16 + cc;
        float bval = bias[n];
        int h = n >> 6, d = n & 63;
#pragma unroll
        for (int r = 0; r < 4; ++r) {
          int m = m0 + wr * 64 + mf * 16 + g * 4 + r;
          int b = m >> 10, s = m & 1023;
          u16 o = f2bf(acc[mf][nf][r] + bval);
          if (which == 0)
            Qh[((((size_t)b * NUM_HEADS + h) * SEQ + s) << 6) + d] = o;
          else
            Kh[((((size_t)b * NUM_HEADS + h) * SEQ + s) << 6) + d] = o;
        }
      }
    }
  } else {
    __syncthreads();
    char* T = (char*)sAB;
#pragma unroll
    for (int mf = 0; mf < 4; ++mf) {
#pragma unroll
      for (int nf = 0; nf < 4; ++nf) {
        int nl = wc * 64 + nf * 16 + cc;
        float bval = bias[n0 + nl];
        int mlb = wr * 64 + mf * 16 + g * 4;
        u16x4 v;
#pragma unroll
        for (int r = 0; r < 4; ++r) v[r] = f2bf(acc[mf][nf][r] + bval);
        int byte = nl * 256 + ((mlb * 2) ^ ((nl & 7) << 4));
        *(u16x4*)(T + byte) = v;
      }
    }
    __syncthreads();
    int nl = tid >> 1, mh = (tid & 1) * 64;
    int b = m0 >> 10, s0 = m0 & 1023;
    u16* dst = &Vt[((size_t)b * 1024 + n0 + nl) * SEQ + s0 + mh];
#pragma unroll
    for (int j2 = 0; j2 < 8; ++j2) {
      int byte = nl * 256 + (((mh + j2 * 8) * 2) ^ ((nl & 7) << 4));
      *(u16x8*)&dst[j2 * 8] = *(const u16x8*)(T + byte);
    }
  }
}

// ---------------- attention pass 1: row sums -> inv_l (32KB K chunks: 4 drains) ----------------
__global__ __launch_bounds__(256, 3) void k_attn1(
    const u16* __restrict__ Qh, const u16* __restrict__ Kh,
    const u16* __restrict__ adder, const int* __restrict__ flags,
    float* __restrict__ invl) {
  __shared__ u16 sQ[128 * 64];     // 16 KB
  __shared__ u16 sK[2][128 * 64];  // 32 KB (two 128-row K tiles per drain)
  int ft = blockIdx.x, h = blockIdx.y, b = blockIdx.z;
  int f0 = ft * 128;
  int bh = b * NUM_HEADS + h;
  const u16* Qg = Qh + ((size_t)bh * SEQ + f0) * 64;
  const u16* Kg = Kh + (size_t)bh * SEQ * 64;
  int tid = threadIdx.x, w = tid >> 6, lane = tid & 63;
  int g = lane >> 4, cc = lane & 15;
  const int fbase = w * 32;

  int flgmask = 0;
#pragma unroll
  for (int tt = 0; tt < 8; ++tt)
    flgmask |= (flags[(b * 8 + ft) * 8 + tt] != 0) << tt;

  int sx[4], srow7[4], scol7[4];
#pragma unroll
  for (int i = 0; i < 4; ++i) {
    int ch = w * 4 + i;
    int x = ch * 1024 + lane * 16;
    sx[i] = ch * 512;
    int r7 = x >> 7;
    int c7 = (x & 127) ^ ((r7 & 7) << 4);
    srow7[i] = r7; scol7[i] = c7 >> 1;
  }

#pragma unroll
  for (int i = 0; i < 4; ++i)
    async16(&sQ[sx[i]], Qg + (size_t)srow7[i] * 64 + scol7[i]);

  float l_run[8];
#pragma unroll
  for (int i = 0; i < 8; ++i) l_run[i] = 0.0f;

  for (int tt4 = 0; tt4 < 4; ++tt4) {
    __syncthreads();
#pragma unroll
    for (int i = 0; i < 4; ++i) {
      async16(&sK[0][sx[i]], Kg + (size_t)(tt4 * 256 + srow7[i]) * 64 + scol7[i]);
      async16(&sK[1][sx[i]], Kg + (size_t)(tt4 * 256 + 128 + srow7[i]) * 64 + scol7[i]);
    }
    VMCNT0;
    __syncthreads();

#pragma unroll
    for (int half = 0; half < 2; ++half) {
      int tt = tt4 * 2 + half;
      f32x4 s[2][8] = {};
#pragma unroll
      for (int kk = 0; kk < 2; ++kk) {
        bf16x8 aq[2], bk8[8];
#pragma unroll
        for (int mf = 0; mf < 2; ++mf) {
          int row = fbase + mf * 16 + cc;
          int colb = (kk * 64 + (g << 4)) ^ ((row & 7) << 4);
          aq[mf] = *(const bf16x8*)&sQ[(row * 128 + colb) >> 1];
        }
#pragma unroll
        for (int nf = 0; nf < 8; ++nf) {
          int row = nf * 16 + cc;
          int colb = (kk * 64 + (g << 4)) ^ ((row & 7) << 4);
          bk8[nf] = *(const bf16x8*)&sK[half][(row * 128 + colb) >> 1];
        }
#pragma unroll
        for (int mf = 0; mf < 2; ++mf)
#pragma unroll
          for (int nf = 0; nf < 8; ++nf)
            s[mf][nf] = __builtin_amdgcn_mfma_f32_16x16x32_bf16(aq[mf], bk8[nf], s[mf][nf], 0, 0, 0);
      }
#pragma unroll
      for (int mf = 0; mf < 2; ++mf)
#pragma unroll
        for (int nf = 0; nf < 8; ++nf)
          s[mf][nf] = s[mf][nf] * C1;
      if ((flgmask >> tt) & 1) {
        for (int mf = 0; mf < 2; ++mf)
          for (int nf = 0; nf < 8; ++nf)
            for (int r = 0; r < 4; ++r) {
              int frow = f0 + fbase + mf * 16 + g * 4 + r;
              int tcol = tt * 128 + nf * 16 + cc;
              s[mf][nf][r] += bf2f(adder[((size_t)b * SEQ + frow) * SEQ + tcol]);
            }
      }
#pragma unroll
      for (int mf = 0; mf < 2; ++mf)
#pragma unroll
        for (int r = 0; r < 4; ++r) {
          float sum = 0.f;
#pragma unroll
          for (int nf = 0; nf < 8; ++nf) sum += exp2f(s[mf][nf][r]);
          sum += __shfl_xor(sum, 1, 16);
          sum += __shfl_xor(sum, 2, 16);
          sum += __shfl_xor(sum, 4, 16);
          sum += __shfl_xor(sum, 8, 16);
          l_run[mf * 4 + r] += sum;
        }
    }
  }

  if (cc == 0) {
#pragma unroll
    for (int mf = 0; mf < 2; ++mf)
#pragma unroll
      for (int r = 0; r < 4; ++r)
        invl[(size_t)bh * SEQ + f0 + fbase + mf * 16 + g * 4 + r] =
            1.0f / l_run[mf * 4 + r];
  }
}

// ---------------- attention pass 2: S recompute, NT float4 probs/ctx, PV ----------------
__global__ __launch_bounds__(256) void k_attn2(
    const u16* __restrict__ Qh, const u16* __restrict__ Kh, const u16* __restrict__ Vt,
    const u16* __restrict__ adder, const int* __restrict__ flags,
    const float* __restrict__ invl,
    float* __restrict__ ctx, float* __restrict__ probs) {
  __shared__ u16 sQ[128 * 64];   // 16 KB
  __shared__ u16 sK[128 * 64];   // 16 KB
  __shared__ u16 sV[64 * 128];   // 16 KB
  __shared__ u16 sP[128 * 128];  // 32 KB (bf16 P; reused as f32 ctx tile at end)
  int ft = blockIdx.x, h = blockIdx.y, b = blockIdx.z;
  int f0 = ft * 128;
  int bh = b * NUM_HEADS + h;
  const u16* Qg = Qh + ((size_t)bh * SEQ + f0) * 64;
  const u16* Kg = Kh + (size_t)bh * SEQ * 64;
  const u16* Vg = Vt + (size_t)bh * 64 * SEQ;
  int tid = threadIdx.x, w = tid >> 6, lane = tid & 63;
  int g = lane >> 4, cc = lane & 15;
  const int fbase = w * 32;

  int flgmask = 0;
#pragma unroll
  for (int tt = 0; tt < 8; ++tt)
    flgmask |= (flags[(b * 8 + ft) * 8 + tt] != 0) << tt;

  int sx[4], srow7[4], scol7[4], srow8[4], scol8[4];
#pragma unroll
  for (int i = 0; i < 4; ++i) {
    int ch = w * 4 + i;
    int x = ch * 1024 + lane * 16;
    sx[i] = ch * 512;
    int r7 = x >> 7;
    int c7 = (x & 127) ^ ((r7 & 7) << 4);
    srow7[i] = r7; scol7[i] = c7 >> 1;
    int r8 = x >> 8;
    int c8 = (x & 255) ^ ((r8 & 7) << 4);
    srow8[i] = r8; scol8[i] = c8 >> 1;
  }

#pragma unroll
  for (int i = 0; i < 4; ++i)
    async16(&sQ[sx[i]], Qg + (size_t)srow7[i] * 64 + scol7[i]);

  float inv_l[8];
#pragma unroll
  for (int mf = 0; mf < 2; ++mf)
#pragma unroll
    for (int r = 0; r < 4; ++r)
      inv_l[mf * 4 + r] =
          invl[(size_t)bh * SEQ + f0 + fbase + mf * 16 + g * 4 + r];

  f32x4 accO[2][4] = {};

  for (int tt = 0; tt < 8; ++tt) {
    __syncthreads();
#pragma unroll
    for (int i = 0; i < 4; ++i) {
      async16(&sK[sx[i]], Kg + (size_t)(tt * 128 + srow7[i]) * 64 + scol7[i]);
      async16(&sV[sx[i]], Vg + (size_t)srow8[i] * SEQ + tt * 128 + scol8[i]);
    }
    VMCNT0;
    __syncthreads();

    f32x4 s[2][8] = {};
#pragma unroll
    for (int kk = 0; kk < 2; ++kk) {
      bf16x8 aq[2], bk8[8];
#pragma unroll
      for (int mf = 0; mf < 2; ++mf) {
        int row = fbase + mf * 16 + cc;
        int colb = (kk * 64 + (g << 4)) ^ ((row & 7) << 4);
        aq[mf] = *(const bf16x8*)&sQ[(row * 128 + colb) >> 1];
      }
#pragma unroll
      for (int nf = 0; nf < 8; ++nf) {
        int row = nf * 16 + cc;
        int colb = (kk * 64 + (g << 4)) ^ ((row & 7) << 4);
        bk8[nf] = *(const bf16x8*)&sK[(row * 128 + colb) >> 1];
      }
#pragma unroll
      for (int mf = 0; mf < 2; ++mf)
#pragma unroll
        for (int nf = 0; nf < 8; ++nf)
          s[mf][nf] = __builtin_amdgcn_mfma_f32_16x16x32_bf16(aq[mf], bk8[nf], s[mf][nf], 0, 0, 0);
    }
#pragma unroll
    for (int mf = 0; mf < 2; ++mf)
#pragma unroll
      for (int nf = 0; nf < 8; ++nf)
        s[mf][nf] = s[mf][nf] * C1;
    if ((flgmask >> tt) & 1) {
      for (int mf = 0; mf < 2; ++mf)
        for (int nf = 0; nf < 8; ++nf)
          for (int r = 0; r < 4; ++r) {
            int frow = f0 + fbase + mf * 16 + g * 4 + r;
            int tcol = tt * 128 + nf * 16 + cc;
            s[mf][nf][r] += bf2f(adder[((size_t)b * SEQ + frow) * SEQ + tcol]);
          }
    }
    // p -> wave-private sP rows (bf16)
#pragma unroll
    for (int mf = 0; mf < 2; ++mf)
#pragma unroll
      for (int nf = 0; nf < 8; ++nf)
#pragma unroll
        for (int r = 0; r < 4; ++r) {
          int idx = mf * 4 + r;
          float p = exp2f(s[mf][nf][r]) * inv_l[idx];
          int frow = fbase + mf * 16 + g * 4 + r;
          int tcol = nf * 16 + cc;
          sP[(frow * 256 + ((tcol * 2) ^ ((frow & 7) << 4))) >> 1] = f2bf(p);
        }
    // coalesced NT probs stores (own wave's rows; intra-wave lgkmcnt handled by compiler)
#pragma unroll
    for (int sw = 0; sw < 8; ++sw) {
      int row = fbase + sw * 4 + (lane >> 4);
      int colb = ((lane & 15) * 16) ^ ((row & 7) << 4);
      u16x8 pv = *(const u16x8*)&sP[(row * 256 + colb) >> 1];
      float* dst = &probs[((size_t)bh * SEQ + f0 + row) * SEQ + tt * 128 + (lane & 15) * 8];
      f32x4 o0 = {bf2f(pv[0]), bf2f(pv[1]), bf2f(pv[2]), bf2f(pv[3])};
      f32x4 o1 = {bf2f(pv[4]), bf2f(pv[5]), bf2f(pv[6]), bf2f(pv[7])};
      ntstore4(dst, o0);
      ntstore4(dst + 4, o1);
    }
#pragma unroll
    for (int ks = 0; ks < 4; ++ks) {
      bf16x8 ap[2], bv8[4];
#pragma unroll
      for (int mf = 0; mf < 2; ++mf) {
        int row = fbase + mf * 16 + cc;
        int colb = (ks * 64 + (g << 4)) ^ ((row & 7) << 4);
        ap[mf] = *(const bf16x8*)&sP[(row * 256 + colb) >> 1];
      }
#pragma unroll
      for (int nf = 0; nf < 4; ++nf) {
        int row = nf * 16 + cc;
        int colb = (ks * 64 + (g << 4)) ^ ((row & 7) << 4);
        bv8[nf] = *(const bf16x8*)&sV[(row * 256 + colb) >> 1];
      }
#pragma unroll
      for (int mf = 0; mf < 2; ++mf)
#pragma unroll
        for (int nf = 0; nf < 4; ++nf)
          accO[mf][nf] = __builtin_amdgcn_mfma_f32_16x16x32_bf16(ap[mf], bv8[nf], accO[mf][nf], 0, 0, 0);
    }
  }

  // ctx epilogue: accO -> sP (f32, wave-private rows) -> NT float4 stores
  __syncthreads();  // all waves done with bf16 sP/PV before retyping
  float* sPf = (float*)sP;
#pragma unroll
  for (int mf = 0; mf < 2; ++mf)
#pragma unroll
    for (int nf = 0; nf < 4; ++nf)
#pragma unroll
      for (int r = 0; r < 4; ++r) {
        int frow = fbase + mf * 16 + g * 4 + r;
        sPf[frow * 64 + nf * 16 + cc] = accO[mf][nf][r];
      }
#pragma unroll
  for (int sw = 0; sw < 8; ++sw) {
    int row = fbase + sw * 4 + (lane >> 4);
    f32x4 v = *(const f32x4*)&sPf[row * 64 + (lane & 15) * 4];
    ntstore4(&ctx[((size_t)b * SEQ + f0 + row) * HIDDEN + h * 64 + (lane & 15) * 4], v);
  }
}

extern "C" void kernel_launch(void* const* d_in, const int* in_sizes, int n_in,
                              void* d_out, int out_size, void* d_ws, size_t ws_size,
                              hipStream_t stream) {
  const float* from = (const float*)d_in[0];
  const float* to   = (const float*)d_in[1];
  const float* mask = (const float*)d_in[2];
  const float* Wq   = (const float*)d_in[3];
  const float* bq   = (const float*)d_in[4];
  const float* Wk   = (const float*)d_in[5];
  const float* bk   = (const float*)d_in[6];
  const float* Wv   = (const float*)d_in[7];
  const float* bv   = (const float*)d_in[8];

  char* ws = (char*)d_ws;
  u16* Af    = (u16*)(ws);
  u16* At    = (u16*)(ws + 8388608);
  u16* Wt    = (u16*)(ws + 16777216);
  u16* adder = (u16*)(ws + 23068672);
  int* flags = (int*)(ws + 31457280);
  u16* Qh    = (u16*)(ws + 31458304);
  u16* Kh    = (u16*)(ws + 39846912);
  u16* Vt    = (u16*)(ws + 48235520);
  float* invl = (float*)(ws);  // reuses Af region (dead after k_gemm)

  float* ctx = (float*)d_out;
  float* probs = ctx + (size_t)BATCH * SEQ * HIDDEN;

  k_prep<<<5120, 256, 0, stream>>>(from, Af, to, At, Wq, Wk, Wv, Wt, mask, adder, flags);
  k_gemm<<<dim3(8, 32, 3), 256, 0, stream>>>(Af, At, Wt, bq, bk, bv, Qh, Kh, Vt);
  k_attn1<<<dim3(8, 16, 4), 256, 0, stream>>>(Qh, Kh, adder, flags, invl);
  k_attn2<<<dim3(8, 16, 4), 256, 0, stream>>>(Qh, Kh, Vt, adder, flags, invl, ctx, probs);
}

// Round 10
// 197.913 us; speedup vs baseline: 1.2208x; 1.2208x over previous
//
#include <hip/hip_runtime.h>

typedef unsigned short u16;
typedef __bf16 bf16x8 __attribute__((ext_vector_type(8)));
typedef float f32x4 __attribute__((ext_vector_type(4)));
typedef u16 u16x8 __attribute__((ext_vector_type(8)));
typedef u16 u16x4 __attribute__((ext_vector_type(4)));

#define NUM_HEADS 16
#define HIDDEN 1024
#define BATCH 4
#define SEQ 1024
// 0.125 * log2(e): fold the 1/sqrt(64) scale and the exp->exp2 conversion
#define C1 0.1803368809109783f
#define LOG2E 1.4426950408889634f

#define VMCNT0 asm volatile("s_waitcnt vmcnt(0)" ::: "memory")

static __device__ __forceinline__ u16 f2bf(float x) {
  unsigned u = __float_as_uint(x);
  u = u + 0x7FFFu + ((u >> 16) & 1u);
  return (u16)(u >> 16);
}
static __device__ __forceinline__ float bf2f(u16 b) {
  return __uint_as_float(((unsigned)b) << 16);
}
static __device__ __forceinline__ void async16(u16* lds, const u16* g) {
  __builtin_amdgcn_global_load_lds(
      (const __attribute__((address_space(1))) void*)g,
      (__attribute__((address_space(3))) void*)lds, 16, 0, 0);
}

// ---------------- merged prep: cvt x2 | wtrans | mask in one launch ----------------
__global__ __launch_bounds__(256) void k_prep(
    const float* __restrict__ from, u16* __restrict__ Af,
    const float* __restrict__ to, u16* __restrict__ At,
    const float* __restrict__ Wq, const float* __restrict__ Wk,
    const float* __restrict__ Wv, u16* __restrict__ Wt,
    const float* __restrict__ mask, u16* __restrict__ adder, int* __restrict__ flags) {
  int bid = blockIdx.x;
  int tid = threadIdx.x;
  if (bid < 4096) {
    const float* in = (bid < 2048) ? from : to;
    u16* out = (bid < 2048) ? Af : At;
    int i = (bid & 2047) * 256 + tid;
    float4 a = ((const float4*)in)[i * 2];
    float4 b = ((const float4*)in)[i * 2 + 1];
    u16x8 v;
    v[0] = f2bf(a.x); v[1] = f2bf(a.y); v[2] = f2bf(a.z); v[3] = f2bf(a.w);
    v[4] = f2bf(b.x); v[5] = f2bf(b.y); v[6] = f2bf(b.z); v[7] = f2bf(b.w);
    *(u16x8*)&out[(size_t)i * 8] = v;
  } else if (bid < 4864) {
    __shared__ float tile[64][65];
    int wid = bid - 4096;
    int z = wid >> 8, rem = wid & 255;
    int x = rem & 15, y = rem >> 4;
    const float* W = (z == 0) ? Wq : (z == 1) ? Wk : Wv;
    u16* out = Wt + (size_t)z * HIDDEN * HIDDEN;
    int k0 = y * 64, n0 = x * 64;
    int r = tid >> 6, c = tid & 63;
#pragma unroll
    for (int i = 0; i < 16; ++i)
      tile[i * 4 + r][c] = W[(size_t)(k0 + i * 4 + r) * HIDDEN + n0 + c];
    __syncthreads();
#pragma unroll
    for (int i = 0; i < 16; ++i)
      out[(size_t)(n0 + i * 4 + r) * HIDDEN + k0 + c] = f2bf(tile[c][i * 4 + r]);
  } else {
    int wid = bid - 4864;
    int tt = wid & 7, ft = (wid >> 3) & 7, b = wid >> 6;
    __shared__ int sflag;
    if (tid == 0) sflag = 0;
    __syncthreads();
    size_t base = ((size_t)b * SEQ + ft * 128) * SEQ + tt * 128;
    int any = 0;
#pragma unroll
    for (int i = 0; i < 16; ++i) {
      int idx = i * 256 + tid;
      int r = idx >> 5, c4 = idx & 31;
      float4 v = *(const float4*)&mask[base + (size_t)r * SEQ + c4 * 4];
      any |= (v.x != 1.0f) | (v.y != 1.0f) | (v.z != 1.0f) | (v.w != 1.0f);
    }
    if (any) sflag = 1;
    __syncthreads();
    if (sflag) {
#pragma unroll
      for (int i = 0; i < 16; ++i) {
        int idx = i * 256 + tid;
        int r = idx >> 5, c4 = idx & 31;
        float4 v = *(const float4*)&mask[base + (size_t)r * SEQ + c4 * 4];
        u16x4 o;
        o[0] = f2bf((1.0f - v.x) * -10000.0f * LOG2E);
        o[1] = f2bf((1.0f - v.y) * -10000.0f * LOG2E);
        o[2] = f2bf((1.0f - v.z) * -10000.0f * LOG2E);
        o[3] = f2bf((1.0f - v.w) * -10000.0f * LOG2E);
        *(u16x4*)&adder[base + (size_t)r * SEQ + c4 * 4] = o;
      }
    }
    if (tid == 0) flags[(b * 8 + ft) * 8 + tt] = sflag;
  }
}

// ---------------- Q GEMM: 128x128 tile, BK=64, single-buffer ----------------
__global__ __launch_bounds__(256) void k_gemmQ(
    const u16* __restrict__ Af, const u16* __restrict__ Wt,
    const float* __restrict__ bq, u16* __restrict__ Qh) {
  __shared__ u16 sA[128 * 64];
  __shared__ u16 sB[128 * 64];
  const u16* A = Af;
  const u16* B = Wt;
  int wg = blockIdx.x + 8 * blockIdx.y;
  int xcd = wg & 7, j = wg >> 3;
  int ntile = j & 7, mstrip = xcd * 4 + (j >> 3);
  int m0 = mstrip * 128, n0 = ntile * 128;
  int tid = threadIdx.x, w = tid >> 6, lane = tid & 63;
  int wr = w >> 1, wc = w & 1;
  int g = lane >> 4, cc = lane & 15;

  f32x4 acc[4][4] = {};

  int sx[4], srow[4], scol[4];
#pragma unroll
  for (int i = 0; i < 4; ++i) {
    int ch = w * 4 + i;
    int x = ch * 1024 + lane * 16;
    int row = x >> 7;
    int colb = (x & 127) ^ ((row & 7) << 4);
    sx[i] = ch * 512;
    srow[i] = row;
    scol[i] = colb >> 1;
  }

  for (int kt = 0; kt < HIDDEN / 64; ++kt) {
    __syncthreads();
#pragma unroll
    for (int i = 0; i < 4; ++i) {
      async16(&sA[sx[i]], A + (size_t)(m0 + srow[i]) * HIDDEN + kt * 64 + scol[i]);
      async16(&sB[sx[i]], B + (size_t)(n0 + srow[i]) * HIDDEN + kt * 64 + scol[i]);
    }
    VMCNT0;
    __syncthreads();
#pragma unroll
    for (int kk = 0; kk < 2; ++kk) {
      bf16x8 af[4], bfr[4];
#pragma unroll
      for (int mf = 0; mf < 4; ++mf) {
        int row = wr * 64 + mf * 16 + cc;
        int colb = (kk * 64 + (g << 4)) ^ ((row & 7) << 4);
        af[mf] = *(const bf16x8*)&sA[(row * 128 + colb) >> 1];
      }
#pragma unroll
      for (int nf = 0; nf < 4; ++nf) {
        int row = wc * 64 + nf * 16 + cc;
        int colb = (kk * 64 + (g << 4)) ^ ((row & 7) << 4);
        bfr[nf] = *(const bf16x8*)&sB[(row * 128 + colb) >> 1];
      }
#pragma unroll
      for (int mf = 0; mf < 4; ++mf)
#pragma unroll
        for (int nf = 0; nf < 4; ++nf)
          acc[mf][nf] = __builtin_amdgcn_mfma_f32_16x16x32_bf16(af[mf], bfr[nf], acc[mf][nf], 0, 0, 0);
    }
  }

#pragma unroll
  for (int mf = 0; mf < 4; ++mf) {
#pragma unroll
    for (int nf = 0; nf < 4; ++nf) {
      int n = n0 + wc * 64 + nf * 16 + cc;
      float bval = bq[n];
      int h = n >> 6, d = n & 63;
#pragma unroll
      for (int r = 0; r < 4; ++r) {
        int m = m0 + wr * 64 + mf * 16 + g * 4 + r;
        int b = m >> 10, s = m & 1023;
        Qh[((((size_t)b * NUM_HEADS + h) * SEQ + s) << 6) + d] = f2bf(acc[mf][nf][r] + bval);
      }
    }
  }
}

// ---------------- fused K+V GEMM: shared A staging, 64 MFMA per drain ----------------
__global__ __launch_bounds__(256) void k_gemmKV(
    const u16* __restrict__ At, const u16* __restrict__ Wt,
    const float* __restrict__ bk_, const float* __restrict__ bv_,
    u16* __restrict__ Kh, u16* __restrict__ Vt) {
  __shared__ u16 sA[128 * 64];   // 16 KB
  __shared__ u16 sBk[128 * 64];  // 16 KB
  __shared__ u16 sBv[128 * 64];  // 16 KB
  const u16* Bk = Wt + (size_t)1 * HIDDEN * HIDDEN;
  const u16* Bv = Wt + (size_t)2 * HIDDEN * HIDDEN;
  int wg = blockIdx.x + 8 * blockIdx.y;
  int xcd = wg & 7, j = wg >> 3;
  int ntile = j & 7, mstrip = xcd * 4 + (j >> 3);
  int m0 = mstrip * 128, n0 = ntile * 128;
  int tid = threadIdx.x, w = tid >> 6, lane = tid & 63;
  int wr = w >> 1, wc = w & 1;
  int g = lane >> 4, cc = lane & 15;

  f32x4 acck[4][4] = {};
  f32x4 accv[4][4] = {};

  int sx[4], srow[4], scol[4];
#pragma unroll
  for (int i = 0; i < 4; ++i) {
    int ch = w * 4 + i;
    int x = ch * 1024 + lane * 16;
    int row = x >> 7;
    int colb = (x & 127) ^ ((row & 7) << 4);
    sx[i] = ch * 512;
    srow[i] = row;
    scol[i] = colb >> 1;
  }

  for (int kt = 0; kt < HIDDEN / 64; ++kt) {
    __syncthreads();
#pragma unroll
    for (int i = 0; i < 4; ++i) {
      async16(&sA[sx[i]], At + (size_t)(m0 + srow[i]) * HIDDEN + kt * 64 + scol[i]);
      async16(&sBk[sx[i]], Bk + (size_t)(n0 + srow[i]) * HIDDEN + kt * 64 + scol[i]);
      async16(&sBv[sx[i]], Bv + (size_t)(n0 + srow[i]) * HIDDEN + kt * 64 + scol[i]);
    }
    VMCNT0;
    __syncthreads();
#pragma unroll
    for (int kk = 0; kk < 2; ++kk) {
      bf16x8 af[4], bkf[4], bvf[4];
#pragma unroll
      for (int mf = 0; mf < 4; ++mf) {
        int row = wr * 64 + mf * 16 + cc;
        int colb = (kk * 64 + (g << 4)) ^ ((row & 7) << 4);
        af[mf] = *(const bf16x8*)&sA[(row * 128 + colb) >> 1];
      }
#pragma unroll
      for (int nf = 0; nf < 4; ++nf) {
        int row = wc * 64 + nf * 16 + cc;
        int colb = (kk * 64 + (g << 4)) ^ ((row & 7) << 4);
        bkf[nf] = *(const bf16x8*)&sBk[(row * 128 + colb) >> 1];
        bvf[nf] = *(const bf16x8*)&sBv[(row * 128 + colb) >> 1];
      }
#pragma unroll
      for (int mf = 0; mf < 4; ++mf)
#pragma unroll
        for (int nf = 0; nf < 4; ++nf) {
          acck[mf][nf] = __builtin_amdgcn_mfma_f32_16x16x32_bf16(af[mf], bkf[nf], acck[mf][nf], 0, 0, 0);
          accv[mf][nf] = __builtin_amdgcn_mfma_f32_16x16x32_bf16(af[mf], bvf[nf], accv[mf][nf], 0, 0, 0);
        }
    }
  }

  // K epilogue: scattered bf16 stores (same as R8 which==1)
#pragma unroll
  for (int mf = 0; mf < 4; ++mf) {
#pragma unroll
    for (int nf = 0; nf < 4; ++nf) {
      int n = n0 + wc * 64 + nf * 16 + cc;
      float bval = bk_[n];
      int h = n >> 6, d = n & 63;
#pragma unroll
      for (int r = 0; r < 4; ++r) {
        int m = m0 + wr * 64 + mf * 16 + g * 4 + r;
        int b = m >> 10, s = m & 1023;
        Kh[((((size_t)b * NUM_HEADS + h) * SEQ + s) << 6) + d] = f2bf(acck[mf][nf][r] + bval);
      }
    }
  }

  // V epilogue: transpose via LDS (reuses sA+sBk as 32KB tile), coalesced stores
  __syncthreads();
  char* T = (char*)sA;
#pragma unroll
  for (int mf = 0; mf < 4; ++mf) {
#pragma unroll
    for (int nf = 0; nf < 4; ++nf) {
      int nl = wc * 64 + nf * 16 + cc;
      float bval = bv_[n0 + nl];
      int mlb = wr * 64 + mf * 16 + g * 4;
      u16x4 v;
#pragma unroll
      for (int r = 0; r < 4; ++r) v[r] = f2bf(accv[mf][nf][r] + bval);
      int byte = nl * 256 + ((mlb * 2) ^ ((nl & 7) << 4));
      *(u16x4*)(T + byte) = v;
    }
  }
  __syncthreads();
  int nl = tid >> 1, mh = (tid & 1) * 64;
  int b = m0 >> 10, s0 = m0 & 1023;
  u16* dst = &Vt[((size_t)b * 1024 + n0 + nl) * SEQ + s0 + mh];
#pragma unroll
  for (int j2 = 0; j2 < 8; ++j2) {
    int byte = nl * 256 + (((mh + j2 * 8) * 2) ^ ((nl & 7) << 4));
    *(u16x8*)&dst[j2 * 8] = *(const u16x8*)(T + byte);
  }
}

// ---------------- attention pass 1: row sums -> inv_l (small LDS, high occupancy) ----------------
__global__ __launch_bounds__(256, 3) void k_attn1(
    const u16* __restrict__ Qh, const u16* __restrict__ Kh,
    const u16* __restrict__ adder, const int* __restrict__ flags,
    float* __restrict__ invl) {
  __shared__ u16 sQ[128 * 64];   // 16 KB
  __shared__ u16 sK[128 * 64];   // 16 KB
  int ft = blockIdx.x, h = blockIdx.y, b = blockIdx.z;
  int f0 = ft * 128;
  int bh = b * NUM_HEADS + h;
  const u16* Qg = Qh + ((size_t)bh * SEQ + f0) * 64;
  const u16* Kg = Kh + (size_t)bh * SEQ * 64;
  int tid = threadIdx.x, w = tid >> 6, lane = tid & 63;
  int g = lane >> 4, cc = lane & 15;
  const int fbase = w * 32;

  int flgmask = 0;
#pragma unroll
  for (int tt = 0; tt < 8; ++tt)
    flgmask |= (flags[(b * 8 + ft) * 8 + tt] != 0) << tt;

  int sx[4], srow7[4], scol7[4];
#pragma unroll
  for (int i = 0; i < 4; ++i) {
    int ch = w * 4 + i;
    int x = ch * 1024 + lane * 16;
    sx[i] = ch * 512;
    int r7 = x >> 7;
    int c7 = (x & 127) ^ ((r7 & 7) << 4);
    srow7[i] = r7; scol7[i] = c7 >> 1;
  }

#pragma unroll
  for (int i = 0; i < 4; ++i)
    async16(&sQ[sx[i]], Qg + (size_t)srow7[i] * 64 + scol7[i]);

  float l_run[8];
#pragma unroll
  for (int i = 0; i < 8; ++i) l_run[i] = 0.0f;

  for (int tt = 0; tt < 8; ++tt) {
    __syncthreads();
#pragma unroll
    for (int i = 0; i < 4; ++i)
      async16(&sK[sx[i]], Kg + (size_t)(tt * 128 + srow7[i]) * 64 + scol7[i]);
    VMCNT0;
    __syncthreads();

    f32x4 s[2][8] = {};
#pragma unroll
    for (int kk = 0; kk < 2; ++kk) {
      bf16x8 aq[2], bk8[8];
#pragma unroll
      for (int mf = 0; mf < 2; ++mf) {
        int row = fbase + mf * 16 + cc;
        int colb = (kk * 64 + (g << 4)) ^ ((row & 7) << 4);
        aq[mf] = *(const bf16x8*)&sQ[(row * 128 + colb) >> 1];
      }
#pragma unroll
      for (int nf = 0; nf < 8; ++nf) {
        int row = nf * 16 + cc;
        int colb = (kk * 64 + (g << 4)) ^ ((row & 7) << 4);
        bk8[nf] = *(const bf16x8*)&sK[(row * 128 + colb) >> 1];
      }
#pragma unroll
      for (int mf = 0; mf < 2; ++mf)
#pragma unroll
        for (int nf = 0; nf < 8; ++nf)
          s[mf][nf] = __builtin_amdgcn_mfma_f32_16x16x32_bf16(aq[mf], bk8[nf], s[mf][nf], 0, 0, 0);
    }
#pragma unroll
    for (int mf = 0; mf < 2; ++mf)
#pragma unroll
      for (int nf = 0; nf < 8; ++nf)
        s[mf][nf] = s[mf][nf] * C1;
    if ((flgmask >> tt) & 1) {
      for (int mf = 0; mf < 2; ++mf)
        for (int nf = 0; nf < 8; ++nf)
          for (int r = 0; r < 4; ++r) {
            int frow = f0 + fbase + mf * 16 + g * 4 + r;
            int tcol = tt * 128 + nf * 16 + cc;
            s[mf][nf][r] += bf2f(adder[((size_t)b * SEQ + frow) * SEQ + tcol]);
          }
    }
#pragma unroll
    for (int mf = 0; mf < 2; ++mf)
#pragma unroll
      for (int r = 0; r < 4; ++r) {
        float sum = 0.f;
#pragma unroll
        for (int nf = 0; nf < 8; ++nf) sum += exp2f(s[mf][nf][r]);
        sum += __shfl_xor(sum, 1, 16);
        sum += __shfl_xor(sum, 2, 16);
        sum += __shfl_xor(sum, 4, 16);
        sum += __shfl_xor(sum, 8, 16);
        l_run[mf * 4 + r] += sum;
      }
  }

  if (cc == 0) {
#pragma unroll
    for (int mf = 0; mf < 2; ++mf)
#pragma unroll
      for (int r = 0; r < 4; ++r)
        invl[(size_t)bh * SEQ + f0 + fbase + mf * 16 + g * 4 + r] =
            1.0f / l_run[mf * 4 + r];
  }
}

// ---------------- attention pass 2: recompute S, write probs, accumulate ctx ----------------
__global__ __launch_bounds__(256) void k_attn2(
    const u16* __restrict__ Qh, const u16* __restrict__ Kh, const u16* __restrict__ Vt,
    const u16* __restrict__ adder, const int* __restrict__ flags,
    const float* __restrict__ invl,
    float* __restrict__ ctx, float* __restrict__ probs) {
  __shared__ u16 sQ[128 * 64];   // 16 KB
  __shared__ u16 sK[128 * 64];   // 16 KB
  __shared__ u16 sV[64 * 128];   // 16 KB
  __shared__ u16 sP[128 * 128];  // 32 KB
  int ft = blockIdx.x, h = blockIdx.y, b = blockIdx.z;
  int f0 = ft * 128;
  int bh = b * NUM_HEADS + h;
  const u16* Qg = Qh + ((size_t)bh * SEQ + f0) * 64;
  const u16* Kg = Kh + (size_t)bh * SEQ * 64;
  const u16* Vg = Vt + (size_t)bh * 64 * SEQ;
  int tid = threadIdx.x, w = tid >> 6, lane = tid & 63;
  int g = lane >> 4, cc = lane & 15;
  const int fbase = w * 32;

  int flgmask = 0;
#pragma unroll
  for (int tt = 0; tt < 8; ++tt)
    flgmask |= (flags[(b * 8 + ft) * 8 + tt] != 0) << tt;

  int sx[4], srow7[4], scol7[4], srow8[4], scol8[4];
#pragma unroll
  for (int i = 0; i < 4; ++i) {
    int ch = w * 4 + i;
    int x = ch * 1024 + lane * 16;
    sx[i] = ch * 512;
    int r7 = x >> 7;
    int c7 = (x & 127) ^ ((r7 & 7) << 4);
    srow7[i] = r7; scol7[i] = c7 >> 1;
    int r8 = x >> 8;
    int c8 = (x & 255) ^ ((r8 & 7) << 4);
    srow8[i] = r8; scol8[i] = c8 >> 1;
  }

#pragma unroll
  for (int i = 0; i < 4; ++i)
    async16(&sQ[sx[i]], Qg + (size_t)srow7[i] * 64 + scol7[i]);

  float inv_l[8];
#pragma unroll
  for (int mf = 0; mf < 2; ++mf)
#pragma unroll
    for (int r = 0; r < 4; ++r)
      inv_l[mf * 4 + r] =
          invl[(size_t)bh * SEQ + f0 + fbase + mf * 16 + g * 4 + r];

  f32x4 accO[2][4] = {};

  for (int tt = 0; tt < 8; ++tt) {
    __syncthreads();
#pragma unroll
    for (int i = 0; i < 4; ++i) {
      async16(&sK[sx[i]], Kg + (size_t)(tt * 128 + srow7[i]) * 64 + scol7[i]);
      async16(&sV[sx[i]], Vg + (size_t)srow8[i] * SEQ + tt * 128 + scol8[i]);
    }
    VMCNT0;
    __syncthreads();

    f32x4 s[2][8] = {};
#pragma unroll
    for (int kk = 0; kk < 2; ++kk) {
      bf16x8 aq[2], bk8[8];
#pragma unroll
      for (int mf = 0; mf < 2; ++mf) {
        int row = fbase + mf * 16 + cc;
        int colb = (kk * 64 + (g << 4)) ^ ((row & 7) << 4);
        aq[mf] = *(const bf16x8*)&sQ[(row * 128 + colb) >> 1];
      }
#pragma unroll
      for (int nf = 0; nf < 8; ++nf) {
        int row = nf * 16 + cc;
        int colb = (kk * 64 + (g << 4)) ^ ((row & 7) << 4);
        bk8[nf] = *(const bf16x8*)&sK[(row * 128 + colb) >> 1];
      }
#pragma unroll
      for (int mf = 0; mf < 2; ++mf)
#pragma unroll
        for (int nf = 0; nf < 8; ++nf)
          s[mf][nf] = __builtin_amdgcn_mfma_f32_16x16x32_bf16(aq[mf], bk8[nf], s[mf][nf], 0, 0, 0);
    }
#pragma unroll
    for (int mf = 0; mf < 2; ++mf)
#pragma unroll
      for (int nf = 0; nf < 8; ++nf)
        s[mf][nf] = s[mf][nf] * C1;
    if ((flgmask >> tt) & 1) {
      for (int mf = 0; mf < 2; ++mf)
        for (int nf = 0; nf < 8; ++nf)
          for (int r = 0; r < 4; ++r) {
            int frow = f0 + fbase + mf * 16 + g * 4 + r;
            int tcol = tt * 128 + nf * 16 + cc;
            s[mf][nf][r] += bf2f(adder[((size_t)b * SEQ + frow) * SEQ + tcol]);
          }
    }
#pragma unroll
    for (int mf = 0; mf < 2; ++mf)
#pragma unroll
      for (int nf = 0; nf < 8; ++nf)
#pragma unroll
        for (int r = 0; r < 4; ++r) {
          int idx = mf * 4 + r;
          float p = exp2f(s[mf][nf][r]) * inv_l[idx];
          int frow = fbase + mf * 16 + g * 4 + r;
          int tcol = nf * 16 + cc;
          probs[(((size_t)bh * SEQ) + f0 + frow) * SEQ + tt * 128 + tcol] = p;
          sP[(frow * 256 + ((tcol * 2) ^ ((frow & 7) << 4))) >> 1] = f2bf(p);
        }
#pragma unroll
    for (int ks = 0; ks < 4; ++ks) {
      bf16x8 ap[2], bv8[4];
#pragma unroll
      for (int mf = 0; mf < 2; ++mf) {
        int row = fbase + mf * 16 + cc;
        int colb = (ks * 64 + (g << 4)) ^ ((row & 7) << 4);
        ap[mf] = *(const bf16x8*)&sP[(row * 256 + colb) >> 1];
      }
#pragma unroll
      for (int nf = 0; nf < 4; ++nf) {
        int row = nf * 16 + cc;
        int colb = (ks * 64 + (g << 4)) ^ ((row & 7) << 4);
        bv8[nf] = *(const bf16x8*)&sV[(row * 256 + colb) >> 1];
      }
#pragma unroll
      for (int mf = 0; mf < 2; ++mf)
#pragma unroll
        for (int nf = 0; nf < 4; ++nf)
          accO[mf][nf] = __builtin_amdgcn_mfma_f32_16x16x32_bf16(ap[mf], bv8[nf], accO[mf][nf], 0, 0, 0);
    }
  }

#pragma unroll
  for (int mf = 0; mf < 2; ++mf)
#pragma unroll
    for (int nf = 0; nf < 4; ++nf)
#pragma unroll
      for (int r = 0; r < 4; ++r) {
        int frow = fbase + mf * 16 + g * 4 + r;
        int d = nf * 16 + cc;
        ctx[((size_t)b * SEQ + f0 + frow) * HIDDEN + h * 64 + d] = accO[mf][nf][r];
      }
}

extern "C" void kernel_launch(void* const* d_in, const int* in_sizes, int n_in,
                              void* d_out, int out_size, void* d_ws, size_t ws_size,
                              hipStream_t stream) {
  const float* from = (const float*)d_in[0];
  const float* to   = (const float*)d_in[1];
  const float* mask = (const float*)d_in[2];
  const float* Wq   = (const float*)d_in[3];
  const float* bq   = (const float*)d_in[4];
  const float* Wk   = (const float*)d_in[5];
  const float* bk   = (const float*)d_in[6];
  const float* Wv   = (const float*)d_in[7];
  const float* bv   = (const float*)d_in[8];

  char* ws = (char*)d_ws;
  u16* Af    = (u16*)(ws);
  u16* At    = (u16*)(ws + 8388608);
  u16* Wt    = (u16*)(ws + 16777216);
  u16* adder = (u16*)(ws + 23068672);
  int* flags = (int*)(ws + 31457280);
  u16* Qh    = (u16*)(ws + 31458304);
  u16* Kh    = (u16*)(ws + 39846912);
  u16* Vt    = (u16*)(ws + 48235520);
  float* invl = (float*)(ws);  // reuses Af region (dead after k_gemmQ)

  float* ctx = (float*)d_out;
  float* probs = ctx + (size_t)BATCH * SEQ * HIDDEN;

  k_prep<<<5120, 256, 0, stream>>>(from, Af, to, At, Wq, Wk, Wv, Wt, mask, adder, flags);
  k_gemmQ<<<dim3(8, 32), 256, 0, stream>>>(Af, Wt, bq, Qh);
  k_gemmKV<<<dim3(8, 32), 256, 0, stream>>>(At, Wt, bk, bv, Kh, Vt);
  k_attn1<<<dim3(8, 16, 4), 256, 0, stream>>>(Qh, Kh, adder, flags, invl);
  k_attn2<<<dim3(8, 16, 4), 256, 0, stream>>>(Qh, Kh, Vt, adder, flags, invl, ctx, probs);
}

// Round 11
// 196.376 us; speedup vs baseline: 1.2303x; 1.0078x over previous
//
#include <hip/hip_runtime.h>

typedef unsigned short u16;
typedef __bf16 bf16x8 __attribute__((ext_vector_type(8)));
typedef float f32x4 __attribute__((ext_vector_type(4)));
typedef u16 u16x8 __attribute__((ext_vector_type(8)));
typedef u16 u16x4 __attribute__((ext_vector_type(4)));

#define NUM_HEADS 16
#define HIDDEN 1024
#define BATCH 4
#define SEQ 1024
// 0.125 * log2(e): fold the 1/sqrt(64) scale and the exp->exp2 conversion
#define C1 0.1803368809109783f
#define LOG2E 1.4426950408889634f

#define VMCNT0 asm volatile("s_waitcnt vmcnt(0)" ::: "memory")

static __device__ __forceinline__ u16 f2bf(float x) {
  unsigned u = __float_as_uint(x);
  u = u + 0x7FFFu + ((u >> 16) & 1u);
  return (u16)(u >> 16);
}
static __device__ __forceinline__ float bf2f(u16 b) {
  return __uint_as_float(((unsigned)b) << 16);
}
static __device__ __forceinline__ void async16(u16* lds, const u16* g) {
  __builtin_amdgcn_global_load_lds(
      (const __attribute__((address_space(1))) void*)g,
      (__attribute__((address_space(3))) void*)lds, 16, 0, 0);
}

// ---------------- merged prep: cvt x2 | wtrans | mask in one launch ----------------
__global__ __launch_bounds__(256) void k_prep(
    const float* __restrict__ from, u16* __restrict__ Af,
    const float* __restrict__ to, u16* __restrict__ At,
    const float* __restrict__ Wq, const float* __restrict__ Wk,
    const float* __restrict__ Wv, u16* __restrict__ Wt,
    const float* __restrict__ mask, u16* __restrict__ adder, int* __restrict__ flags) {
  int bid = blockIdx.x;
  int tid = threadIdx.x;
  if (bid < 4096) {
    const float* in = (bid < 2048) ? from : to;
    u16* out = (bid < 2048) ? Af : At;
    int i = (bid & 2047) * 256 + tid;
    float4 a = ((const float4*)in)[i * 2];
    float4 b = ((const float4*)in)[i * 2 + 1];
    u16x8 v;
    v[0] = f2bf(a.x); v[1] = f2bf(a.y); v[2] = f2bf(a.z); v[3] = f2bf(a.w);
    v[4] = f2bf(b.x); v[5] = f2bf(b.y); v[6] = f2bf(b.z); v[7] = f2bf(b.w);
    *(u16x8*)&out[(size_t)i * 8] = v;
  } else if (bid < 4864) {
    __shared__ float tile[64][65];
    int wid = bid - 4096;
    int z = wid >> 8, rem = wid & 255;
    int x = rem & 15, y = rem >> 4;
    const float* W = (z == 0) ? Wq : (z == 1) ? Wk : Wv;
    u16* out = Wt + (size_t)z * HIDDEN * HIDDEN;
    int k0 = y * 64, n0 = x * 64;
    int r = tid >> 6, c = tid & 63;
#pragma unroll
    for (int i = 0; i < 16; ++i)
      tile[i * 4 + r][c] = W[(size_t)(k0 + i * 4 + r) * HIDDEN + n0 + c];
    __syncthreads();
#pragma unroll
    for (int i = 0; i < 16; ++i)
      out[(size_t)(n0 + i * 4 + r) * HIDDEN + k0 + c] = f2bf(tile[c][i * 4 + r]);
  } else {
    int wid = bid - 4864;
    int tt = wid & 7, ft = (wid >> 3) & 7, b = wid >> 6;
    __shared__ int sflag;
    if (tid == 0) sflag = 0;
    __syncthreads();
    size_t base = ((size_t)b * SEQ + ft * 128) * SEQ + tt * 128;
    int any = 0;
#pragma unroll
    for (int i = 0; i < 16; ++i) {
      int idx = i * 256 + tid;
      int r = idx >> 5, c4 = idx & 31;
      float4 v = *(const float4*)&mask[base + (size_t)r * SEQ + c4 * 4];
      any |= (v.x != 1.0f) | (v.y != 1.0f) | (v.z != 1.0f) | (v.w != 1.0f);
    }
    if (any) sflag = 1;
    __syncthreads();
    if (sflag) {
#pragma unroll
      for (int i = 0; i < 16; ++i) {
        int idx = i * 256 + tid;
        int r = idx >> 5, c4 = idx & 31;
        float4 v = *(const float4*)&mask[base + (size_t)r * SEQ + c4 * 4];
        u16x4 o;
        o[0] = f2bf((1.0f - v.x) * -10000.0f * LOG2E);
        o[1] = f2bf((1.0f - v.y) * -10000.0f * LOG2E);
        o[2] = f2bf((1.0f - v.z) * -10000.0f * LOG2E);
        o[3] = f2bf((1.0f - v.w) * -10000.0f * LOG2E);
        *(u16x4*)&adder[base + (size_t)r * SEQ + c4 * 4] = o;
      }
    }
    if (tid == 0) flags[(b * 8 + ft) * 8 + tt] = sflag;
  }
}

// ---------------- merged Q|KV GEMM: one 512-block launch, ~2 blocks/CU ----------------
// bid<256: Q GEMM (from @ Wq). bid>=256: fused K+V GEMM (to @ Wk|Wv, shared A).
__global__ __launch_bounds__(256) void k_gemmQKV(
    const u16* __restrict__ Af, const u16* __restrict__ At,
    const u16* __restrict__ Wt,
    const float* __restrict__ bq, const float* __restrict__ bk_, const float* __restrict__ bv_,
    u16* __restrict__ Qh, u16* __restrict__ Kh, u16* __restrict__ Vt) {
  __shared__ u16 lds[3 * 128 * 64];  // 48 KB
  int bid = blockIdx.x;
  int which = bid >> 8;              // 0 = Q, 1 = KV (block-uniform)
  int wg = bid & 255;
  int xcd = wg & 7, j = wg >> 3;
  int ntile = j & 7, mstrip = xcd * 4 + (j >> 3);
  int m0 = mstrip * 128, n0 = ntile * 128;
  int tid = threadIdx.x, w = tid >> 6, lane = tid & 63;
  int wr = w >> 1, wc = w & 1;
  int g = lane >> 4, cc = lane & 15;

  int sx[4], srow[4], scol[4];
#pragma unroll
  for (int i = 0; i < 4; ++i) {
    int ch = w * 4 + i;
    int x = ch * 1024 + lane * 16;
    int row = x >> 7;
    int colb = (x & 127) ^ ((row & 7) << 4);
    sx[i] = ch * 512;
    srow[i] = row;
    scol[i] = colb >> 1;
  }

  if (which == 0) {
    // ---------------- Q path ----------------
    u16* sA = lds;
    u16* sB = lds + 8192;
    const u16* A = Af;
    const u16* B = Wt;
    f32x4 acc[4][4] = {};

    for (int kt = 0; kt < HIDDEN / 64; ++kt) {
      __syncthreads();
#pragma unroll
      for (int i = 0; i < 4; ++i) {
        async16(&sA[sx[i]], A + (size_t)(m0 + srow[i]) * HIDDEN + kt * 64 + scol[i]);
        async16(&sB[sx[i]], B + (size_t)(n0 + srow[i]) * HIDDEN + kt * 64 + scol[i]);
      }
      VMCNT0;
      __syncthreads();
#pragma unroll
      for (int kk = 0; kk < 2; ++kk) {
        bf16x8 af[4], bfr[4];
#pragma unroll
        for (int mf = 0; mf < 4; ++mf) {
          int row = wr * 64 + mf * 16 + cc;
          int colb = (kk * 64 + (g << 4)) ^ ((row & 7) << 4);
          af[mf] = *(const bf16x8*)&sA[(row * 128 + colb) >> 1];
        }
#pragma unroll
        for (int nf = 0; nf < 4; ++nf) {
          int row = wc * 64 + nf * 16 + cc;
          int colb = (kk * 64 + (g << 4)) ^ ((row & 7) << 4);
          bfr[nf] = *(const bf16x8*)&sB[(row * 128 + colb) >> 1];
        }
#pragma unroll
        for (int mf = 0; mf < 4; ++mf)
#pragma unroll
          for (int nf = 0; nf < 4; ++nf)
            acc[mf][nf] = __builtin_amdgcn_mfma_f32_16x16x32_bf16(af[mf], bfr[nf], acc[mf][nf], 0, 0, 0);
      }
    }

#pragma unroll
    for (int mf = 0; mf < 4; ++mf) {
#pragma unroll
      for (int nf = 0; nf < 4; ++nf) {
        int n = n0 + wc * 64 + nf * 16 + cc;
        float bval = bq[n];
        int h = n >> 6, d = n & 63;
#pragma unroll
        for (int r = 0; r < 4; ++r) {
          int m = m0 + wr * 64 + mf * 16 + g * 4 + r;
          int b = m >> 10, s = m & 1023;
          Qh[((((size_t)b * NUM_HEADS + h) * SEQ + s) << 6) + d] = f2bf(acc[mf][nf][r] + bval);
        }
      }
    }
  } else {
    // ---------------- KV path: shared A staging, 64 MFMA per drain ----------------
    u16* sA = lds;
    u16* sBk = lds + 8192;
    u16* sBv = lds + 16384;
    const u16* Bk = Wt + (size_t)1 * HIDDEN * HIDDEN;
    const u16* Bv = Wt + (size_t)2 * HIDDEN * HIDDEN;
    f32x4 acck[4][4] = {};
    f32x4 accv[4][4] = {};

    for (int kt = 0; kt < HIDDEN / 64; ++kt) {
      __syncthreads();
#pragma unroll
      for (int i = 0; i < 4; ++i) {
        async16(&sA[sx[i]], At + (size_t)(m0 + srow[i]) * HIDDEN + kt * 64 + scol[i]);
        async16(&sBk[sx[i]], Bk + (size_t)(n0 + srow[i]) * HIDDEN + kt * 64 + scol[i]);
        async16(&sBv[sx[i]], Bv + (size_t)(n0 + srow[i]) * HIDDEN + kt * 64 + scol[i]);
      }
      VMCNT0;
      __syncthreads();
#pragma unroll
      for (int kk = 0; kk < 2; ++kk) {
        bf16x8 af[4], bkf[4], bvf[4];
#pragma unroll
        for (int mf = 0; mf < 4; ++mf) {
          int row = wr * 64 + mf * 16 + cc;
          int colb = (kk * 64 + (g << 4)) ^ ((row & 7) << 4);
          af[mf] = *(const bf16x8*)&sA[(row * 128 + colb) >> 1];
        }
#pragma unroll
        for (int nf = 0; nf < 4; ++nf) {
          int row = wc * 64 + nf * 16 + cc;
          int colb = (kk * 64 + (g << 4)) ^ ((row & 7) << 4);
          bkf[nf] = *(const bf16x8*)&sBk[(row * 128 + colb) >> 1];
          bvf[nf] = *(const bf16x8*)&sBv[(row * 128 + colb) >> 1];
        }
#pragma unroll
        for (int mf = 0; mf < 4; ++mf)
#pragma unroll
          for (int nf = 0; nf < 4; ++nf) {
            acck[mf][nf] = __builtin_amdgcn_mfma_f32_16x16x32_bf16(af[mf], bkf[nf], acck[mf][nf], 0, 0, 0);
            accv[mf][nf] = __builtin_amdgcn_mfma_f32_16x16x32_bf16(af[mf], bvf[nf], accv[mf][nf], 0, 0, 0);
          }
      }
    }

    // K epilogue: scattered bf16 stores
#pragma unroll
    for (int mf = 0; mf < 4; ++mf) {
#pragma unroll
      for (int nf = 0; nf < 4; ++nf) {
        int n = n0 + wc * 64 + nf * 16 + cc;
        float bval = bk_[n];
        int h = n >> 6, d = n & 63;
#pragma unroll
        for (int r = 0; r < 4; ++r) {
          int m = m0 + wr * 64 + mf * 16 + g * 4 + r;
          int b = m >> 10, s = m & 1023;
          Kh[((((size_t)b * NUM_HEADS + h) * SEQ + s) << 6) + d] = f2bf(acck[mf][nf][r] + bval);
        }
      }
    }

    // V epilogue: transpose via LDS, coalesced stores along s
    __syncthreads();
    char* T = (char*)lds;
#pragma unroll
    for (int mf = 0; mf < 4; ++mf) {
#pragma unroll
      for (int nf = 0; nf < 4; ++nf) {
        int nl = wc * 64 + nf * 16 + cc;
        float bval = bv_[n0 + nl];
        int mlb = wr * 64 + mf * 16 + g * 4;
        u16x4 v;
#pragma unroll
        for (int r = 0; r < 4; ++r) v[r] = f2bf(accv[mf][nf][r] + bval);
        int byte = nl * 256 + ((mlb * 2) ^ ((nl & 7) << 4));
        *(u16x4*)(T + byte) = v;
      }
    }
    __syncthreads();
    int nl = tid >> 1, mh = (tid & 1) * 64;
    int b = m0 >> 10, s0 = m0 & 1023;
    u16* dst = &Vt[((size_t)b * 1024 + n0 + nl) * SEQ + s0 + mh];
#pragma unroll
    for (int j2 = 0; j2 < 8; ++j2) {
      int byte = nl * 256 + (((mh + j2 * 8) * 2) ^ ((nl & 7) << 4));
      *(u16x8*)&dst[j2 * 8] = *(const u16x8*)(T + byte);
    }
  }
}

// ---------------- attention pass 1: row sums -> inv_l (small LDS, high occupancy) ----------------
__global__ __launch_bounds__(256, 3) void k_attn1(
    const u16* __restrict__ Qh, const u16* __restrict__ Kh,
    const u16* __restrict__ adder, const int* __restrict__ flags,
    float* __restrict__ invl) {
  __shared__ u16 sQ[128 * 64];   // 16 KB
  __shared__ u16 sK[128 * 64];   // 16 KB
  int ft = blockIdx.x, h = blockIdx.y, b = blockIdx.z;
  int f0 = ft * 128;
  int bh = b * NUM_HEADS + h;
  const u16* Qg = Qh + ((size_t)bh * SEQ + f0) * 64;
  const u16* Kg = Kh + (size_t)bh * SEQ * 64;
  int tid = threadIdx.x, w = tid >> 6, lane = tid & 63;
  int g = lane >> 4, cc = lane & 15;
  const int fbase = w * 32;

  int flgmask = 0;
#pragma unroll
  for (int tt = 0; tt < 8; ++tt)
    flgmask |= (flags[(b * 8 + ft) * 8 + tt] != 0) << tt;

  int sx[4], srow7[4], scol7[4];
#pragma unroll
  for (int i = 0; i < 4; ++i) {
    int ch = w * 4 + i;
    int x = ch * 1024 + lane * 16;
    sx[i] = ch * 512;
    int r7 = x >> 7;
    int c7 = (x & 127) ^ ((r7 & 7) << 4);
    srow7[i] = r7; scol7[i] = c7 >> 1;
  }

#pragma unroll
  for (int i = 0; i < 4; ++i)
    async16(&sQ[sx[i]], Qg + (size_t)srow7[i] * 64 + scol7[i]);

  float l_run[8];
#pragma unroll
  for (int i = 0; i < 8; ++i) l_run[i] = 0.0f;

  for (int tt = 0; tt < 8; ++tt) {
    __syncthreads();
#pragma unroll
    for (int i = 0; i < 4; ++i)
      async16(&sK[sx[i]], Kg + (size_t)(tt * 128 + srow7[i]) * 64 + scol7[i]);
    VMCNT0;
    __syncthreads();

    f32x4 s[2][8] = {};
#pragma unroll
    for (int kk = 0; kk < 2; ++kk) {
      bf16x8 aq[2], bk8[8];
#pragma unroll
      for (int mf = 0; mf < 2; ++mf) {
        int row = fbase + mf * 16 + cc;
        int colb = (kk * 64 + (g << 4)) ^ ((row & 7) << 4);
        aq[mf] = *(const bf16x8*)&sQ[(row * 128 + colb) >> 1];
      }
#pragma unroll
      for (int nf = 0; nf < 8; ++nf) {
        int row = nf * 16 + cc;
        int colb = (kk * 64 + (g << 4)) ^ ((row & 7) << 4);
        bk8[nf] = *(const bf16x8*)&sK[(row * 128 + colb) >> 1];
      }
#pragma unroll
      for (int mf = 0; mf < 2; ++mf)
#pragma unroll
        for (int nf = 0; nf < 8; ++nf)
          s[mf][nf] = __builtin_amdgcn_mfma_f32_16x16x32_bf16(aq[mf], bk8[nf], s[mf][nf], 0, 0, 0);
    }
#pragma unroll
    for (int mf = 0; mf < 2; ++mf)
#pragma unroll
      for (int nf = 0; nf < 8; ++nf)
        s[mf][nf] = s[mf][nf] * C1;
    if ((flgmask >> tt) & 1) {
      for (int mf = 0; mf < 2; ++mf)
        for (int nf = 0; nf < 8; ++nf)
          for (int r = 0; r < 4; ++r) {
            int frow = f0 + fbase + mf * 16 + g * 4 + r;
            int tcol = tt * 128 + nf * 16 + cc;
            s[mf][nf][r] += bf2f(adder[((size_t)b * SEQ + frow) * SEQ + tcol]);
          }
    }
#pragma unroll
    for (int mf = 0; mf < 2; ++mf)
#pragma unroll
      for (int r = 0; r < 4; ++r) {
        float sum = 0.f;
#pragma unroll
        for (int nf = 0; nf < 8; ++nf) sum += exp2f(s[mf][nf][r]);
        sum += __shfl_xor(sum, 1, 16);
        sum += __shfl_xor(sum, 2, 16);
        sum += __shfl_xor(sum, 4, 16);
        sum += __shfl_xor(sum, 8, 16);
        l_run[mf * 4 + r] += sum;
      }
  }

  if (cc == 0) {
#pragma unroll
    for (int mf = 0; mf < 2; ++mf)
#pragma unroll
      for (int r = 0; r < 4; ++r)
        invl[(size_t)bh * SEQ + f0 + fbase + mf * 16 + g * 4 + r] =
            1.0f / l_run[mf * 4 + r];
  }
}

// ---------------- attention pass 2: recompute S, write probs, accumulate ctx ----------------
__global__ __launch_bounds__(256) void k_attn2(
    const u16* __restrict__ Qh, const u16* __restrict__ Kh, const u16* __restrict__ Vt,
    const u16* __restrict__ adder, const int* __restrict__ flags,
    const float* __restrict__ invl,
    float* __restrict__ ctx, float* __restrict__ probs) {
  __shared__ u16 sQ[128 * 64];   // 16 KB
  __shared__ u16 sK[128 * 64];   // 16 KB
  __shared__ u16 sV[64 * 128];   // 16 KB
  __shared__ u16 sP[128 * 128];  // 32 KB
  int ft = blockIdx.x, h = blockIdx.y, b = blockIdx.z;
  int f0 = ft * 128;
  int bh = b * NUM_HEADS + h;
  const u16* Qg = Qh + ((size_t)bh * SEQ + f0) * 64;
  const u16* Kg = Kh + (size_t)bh * SEQ * 64;
  const u16* Vg = Vt + (size_t)bh * 64 * SEQ;
  int tid = threadIdx.x, w = tid >> 6, lane = tid & 63;
  int g = lane >> 4, cc = lane & 15;
  const int fbase = w * 32;

  int flgmask = 0;
#pragma unroll
  for (int tt = 0; tt < 8; ++tt)
    flgmask |= (flags[(b * 8 + ft) * 8 + tt] != 0) << tt;

  int sx[4], srow7[4], scol7[4], srow8[4], scol8[4];
#pragma unroll
  for (int i = 0; i < 4; ++i) {
    int ch = w * 4 + i;
    int x = ch * 1024 + lane * 16;
    sx[i] = ch * 512;
    int r7 = x >> 7;
    int c7 = (x & 127) ^ ((r7 & 7) << 4);
    srow7[i] = r7; scol7[i] = c7 >> 1;
    int r8 = x >> 8;
    int c8 = (x & 255) ^ ((r8 & 7) << 4);
    srow8[i] = r8; scol8[i] = c8 >> 1;
  }

#pragma unroll
  for (int i = 0; i < 4; ++i)
    async16(&sQ[sx[i]], Qg + (size_t)srow7[i] * 64 + scol7[i]);

  float inv_l[8];
#pragma unroll
  for (int mf = 0; mf < 2; ++mf)
#pragma unroll
    for (int r = 0; r < 4; ++r)
      inv_l[mf * 4 + r] =
          invl[(size_t)bh * SEQ + f0 + fbase + mf * 16 + g * 4 + r];

  f32x4 accO[2][4] = {};

  for (int tt = 0; tt < 8; ++tt) {
    __syncthreads();
#pragma unroll
    for (int i = 0; i < 4; ++i) {
      async16(&sK[sx[i]], Kg + (size_t)(tt * 128 + srow7[i]) * 64 + scol7[i]);
      async16(&sV[sx[i]], Vg + (size_t)srow8[i] * SEQ + tt * 128 + scol8[i]);
    }
    VMCNT0;
    __syncthreads();

    f32x4 s[2][8] = {};
#pragma unroll
    for (int kk = 0; kk < 2; ++kk) {
      bf16x8 aq[2], bk8[8];
#pragma unroll
      for (int mf = 0; mf < 2; ++mf) {
        int row = fbase + mf * 16 + cc;
        int colb = (kk * 64 + (g << 4)) ^ ((row & 7) << 4);
        aq[mf] = *(const bf16x8*)&sQ[(row * 128 + colb) >> 1];
      }
#pragma unroll
      for (int nf = 0; nf < 8; ++nf) {
        int row = nf * 16 + cc;
        int colb = (kk * 64 + (g << 4)) ^ ((row & 7) << 4);
        bk8[nf] = *(const bf16x8*)&sK[(row * 128 + colb) >> 1];
      }
#pragma unroll
      for (int mf = 0; mf < 2; ++mf)
#pragma unroll
        for (int nf = 0; nf < 8; ++nf)
          s[mf][nf] = __builtin_amdgcn_mfma_f32_16x16x32_bf16(aq[mf], bk8[nf], s[mf][nf], 0, 0, 0);
    }
#pragma unroll
    for (int mf = 0; mf < 2; ++mf)
#pragma unroll
      for (int nf = 0; nf < 8; ++nf)
        s[mf][nf] = s[mf][nf] * C1;
    if ((flgmask >> tt) & 1) {
      for (int mf = 0; mf < 2; ++mf)
        for (int nf = 0; nf < 8; ++nf)
          for (int r = 0; r < 4; ++r) {
            int frow = f0 + fbase + mf * 16 + g * 4 + r;
            int tcol = tt * 128 + nf * 16 + cc;
            s[mf][nf][r] += bf2f(adder[((size_t)b * SEQ + frow) * SEQ + tcol]);
          }
    }
#pragma unroll
    for (int mf = 0; mf < 2; ++mf)
#pragma unroll
      for (int nf = 0; nf < 8; ++nf)
#pragma unroll
        for (int r = 0; r < 4; ++r) {
          int idx = mf * 4 + r;
          float p = exp2f(s[mf][nf][r]) * inv_l[idx];
          int frow = fbase + mf * 16 + g * 4 + r;
          int tcol = nf * 16 + cc;
          probs[(((size_t)bh * SEQ) + f0 + frow) * SEQ + tt * 128 + tcol] = p;
          sP[(frow * 256 + ((tcol * 2) ^ ((frow & 7) << 4))) >> 1] = f2bf(p);
        }
#pragma unroll
    for (int ks = 0; ks < 4; ++ks) {
      bf16x8 ap[2], bv8[4];
#pragma unroll
      for (int mf = 0; mf < 2; ++mf) {
        int row = fbase + mf * 16 + cc;
        int colb = (ks * 64 + (g << 4)) ^ ((row & 7) << 4);
        ap[mf] = *(const bf16x8*)&sP[(row * 256 + colb) >> 1];
      }
#pragma unroll
      for (int nf = 0; nf < 4; ++nf) {
        int row = nf * 16 + cc;
        int colb = (ks * 64 + (g << 4)) ^ ((row & 7) << 4);
        bv8[nf] = *(const bf16x8*)&sV[(row * 256 + colb) >> 1];
      }
#pragma unroll
      for (int mf = 0; mf < 2; ++mf)
#pragma unroll
        for (int nf = 0; nf < 4; ++nf)
          accO[mf][nf] = __builtin_amdgcn_mfma_f32_16x16x32_bf16(ap[mf], bv8[nf], accO[mf][nf], 0, 0, 0);
    }
  }

#pragma unroll
  for (int mf = 0; mf < 2; ++mf)
#pragma unroll
    for (int nf = 0; nf < 4; ++nf)
#pragma unroll
      for (int r = 0; r < 4; ++r) {
        int frow = fbase + mf * 16 + g * 4 + r;
        int d = nf * 16 + cc;
        ctx[((size_t)b * SEQ + f0 + frow) * HIDDEN + h * 64 + d] = accO[mf][nf][r];
      }
}

extern "C" void kernel_launch(void* const* d_in, const int* in_sizes, int n_in,
                              void* d_out, int out_size, void* d_ws, size_t ws_size,
                              hipStream_t stream) {
  const float* from = (const float*)d_in[0];
  const float* to   = (const float*)d_in[1];
  const float* mask = (const float*)d_in[2];
  const float* Wq   = (const float*)d_in[3];
  const float* bq   = (const float*)d_in[4];
  const float* Wk   = (const float*)d_in[5];
  const float* bk   = (const float*)d_in[6];
  const float* Wv   = (const float*)d_in[7];
  const float* bv   = (const float*)d_in[8];

  char* ws = (char*)d_ws;
  u16* Af    = (u16*)(ws);
  u16* At    = (u16*)(ws + 8388608);
  u16* Wt    = (u16*)(ws + 16777216);
  u16* adder = (u16*)(ws + 23068672);
  int* flags = (int*)(ws + 31457280);
  u16* Qh    = (u16*)(ws + 31458304);
  u16* Kh    = (u16*)(ws + 39846912);
  u16* Vt    = (u16*)(ws + 48235520);
  float* invl = (float*)(ws);  // reuses Af region (dead after k_gemmQKV)

  float* ctx = (float*)d_out;
  float* probs = ctx + (size_t)BATCH * SEQ * HIDDEN;

  k_prep<<<5120, 256, 0, stream>>>(from, Af, to, At, Wq, Wk, Wv, Wt, mask, adder, flags);
  k_gemmQKV<<<512, 256, 0, stream>>>(Af, At, Wt, bq, bk, bv, Qh, Kh, Vt);
  k_attn1<<<dim3(8, 16, 4), 256, 0, stream>>>(Qh, Kh, adder, flags, invl);
  k_attn2<<<dim3(8, 16, 4), 256, 0, stream>>>(Qh, Kh, Vt, adder, flags, invl, ctx, probs);
}

// Round 12
// 172.371 us; speedup vs baseline: 1.4016x; 1.1393x over previous
//
#include <hip/hip_runtime.h>

typedef unsigned short u16;
typedef __bf16 bf16x8 __attribute__((ext_vector_type(8)));
typedef float f32x4 __attribute__((ext_vector_type(4)));
typedef u16 u16x8 __attribute__((ext_vector_type(8)));
typedef u16 u16x4 __attribute__((ext_vector_type(4)));

#define NUM_HEADS 16
#define HIDDEN 1024
#define BATCH 4
#define SEQ 1024
// 0.125 * log2(e): fold the 1/sqrt(64) scale and the exp->exp2 conversion
#define C1 0.1803368809109783f
#define LOG2E 1.4426950408889634f

#define VMCNT0 asm volatile("s_waitcnt vmcnt(0)" ::: "memory")

static __device__ __forceinline__ u16 f2bf(float x) {
  unsigned u = __float_as_uint(x);
  u = u + 0x7FFFu + ((u >> 16) & 1u);
  return (u16)(u >> 16);
}
static __device__ __forceinline__ float bf2f(u16 b) {
  return __uint_as_float(((unsigned)b) << 16);
}
static __device__ __forceinline__ void async16(u16* lds, const u16* g) {
  __builtin_amdgcn_global_load_lds(
      (const __attribute__((address_space(1))) void*)g,
      (__attribute__((address_space(3))) void*)lds, 16, 0, 0);
}

// ---------------- merged prep: cvt x2 | wtrans | mask in one launch ----------------
__global__ __launch_bounds__(256) void k_prep(
    const float* __restrict__ from, u16* __restrict__ Af,
    const float* __restrict__ to, u16* __restrict__ At,
    const float* __restrict__ Wq, const float* __restrict__ Wk,
    const float* __restrict__ Wv, u16* __restrict__ Wt,
    const float* __restrict__ mask, u16* __restrict__ adder, int* __restrict__ flags) {
  int bid = blockIdx.x;
  int tid = threadIdx.x;
  if (bid < 4096) {
    const float* in = (bid < 2048) ? from : to;
    u16* out = (bid < 2048) ? Af : At;
    int i = (bid & 2047) * 256 + tid;
    float4 a = ((const float4*)in)[i * 2];
    float4 b = ((const float4*)in)[i * 2 + 1];
    u16x8 v;
    v[0] = f2bf(a.x); v[1] = f2bf(a.y); v[2] = f2bf(a.z); v[3] = f2bf(a.w);
    v[4] = f2bf(b.x); v[5] = f2bf(b.y); v[6] = f2bf(b.z); v[7] = f2bf(b.w);
    *(u16x8*)&out[(size_t)i * 8] = v;
  } else if (bid < 4864) {
    __shared__ float tile[64][65];
    int wid = bid - 4096;
    int z = wid >> 8, rem = wid & 255;
    int x = rem & 15, y = rem >> 4;
    const float* W = (z == 0) ? Wq : (z == 1) ? Wk : Wv;
    u16* out = Wt + (size_t)z * HIDDEN * HIDDEN;
    int k0 = y * 64, n0 = x * 64;
    int r = tid >> 6, c = tid & 63;
#pragma unroll
    for (int i = 0; i < 16; ++i)
      tile[i * 4 + r][c] = W[(size_t)(k0 + i * 4 + r) * HIDDEN + n0 + c];
    __syncthreads();
#pragma unroll
    for (int i = 0; i < 16; ++i)
      out[(size_t)(n0 + i * 4 + r) * HIDDEN + k0 + c] = f2bf(tile[c][i * 4 + r]);
  } else {
    int wid = bid - 4864;
    int tt = wid & 7, ft = (wid >> 3) & 7, b = wid >> 6;
    __shared__ int sflag;
    if (tid == 0) sflag = 0;
    __syncthreads();
    size_t base = ((size_t)b * SEQ + ft * 128) * SEQ + tt * 128;
    int any = 0;
#pragma unroll
    for (int i = 0; i < 16; ++i) {
      int idx = i * 256 + tid;
      int r = idx >> 5, c4 = idx & 31;
      float4 v = *(const float4*)&mask[base + (size_t)r * SEQ + c4 * 4];
      any |= (v.x != 1.0f) | (v.y != 1.0f) | (v.z != 1.0f) | (v.w != 1.0f);
    }
    if (any) sflag = 1;
    __syncthreads();
    if (sflag) {
#pragma unroll
      for (int i = 0; i < 16; ++i) {
        int idx = i * 256 + tid;
        int r = idx >> 5, c4 = idx & 31;
        float4 v = *(const float4*)&mask[base + (size_t)r * SEQ + c4 * 4];
        u16x4 o;
        o[0] = f2bf((1.0f - v.x) * -10000.0f * LOG2E);
        o[1] = f2bf((1.0f - v.y) * -10000.0f * LOG2E);
        o[2] = f2bf((1.0f - v.z) * -10000.0f * LOG2E);
        o[3] = f2bf((1.0f - v.w) * -10000.0f * LOG2E);
        *(u16x4*)&adder[base + (size_t)r * SEQ + c4 * 4] = o;
      }
    }
    if (tid == 0) flags[(b * 8 + ft) * 8 + tt] = sflag;
  }
}

// ---------------- merged Q|K GEMM: 512 blocks, one uniform code path ----------------
// bid<256: Q = from @ Wq -> Qh.  bid>=256: K = to @ Wk -> Kh.
__global__ __launch_bounds__(256) void k_gemmQK(
    const u16* __restrict__ Af, const u16* __restrict__ At,
    const u16* __restrict__ Wt,
    const float* __restrict__ bq, const float* __restrict__ bk_,
    u16* __restrict__ Qh, u16* __restrict__ Kh) {
  __shared__ u16 sA[128 * 64];
  __shared__ u16 sB[128 * 64];
  int bid = blockIdx.x;
  int which = bid >> 8;  // block-uniform
  const u16* A = which ? At : Af;
  const u16* B = Wt + (size_t)which * HIDDEN * HIDDEN;
  const float* bias = which ? bk_ : bq;
  u16* out = which ? Kh : Qh;
  int wg = bid & 255;
  int xcd = wg & 7, j = wg >> 3;
  int ntile = j & 7, mstrip = xcd * 4 + (j >> 3);
  int m0 = mstrip * 128, n0 = ntile * 128;
  int tid = threadIdx.x, w = tid >> 6, lane = tid & 63;
  int wr = w >> 1, wc = w & 1;
  int g = lane >> 4, cc = lane & 15;

  f32x4 acc[4][4] = {};

  int sx[4], srow[4], scol[4];
#pragma unroll
  for (int i = 0; i < 4; ++i) {
    int ch = w * 4 + i;
    int x = ch * 1024 + lane * 16;
    int row = x >> 7;
    int colb = (x & 127) ^ ((row & 7) << 4);
    sx[i] = ch * 512;
    srow[i] = row;
    scol[i] = colb >> 1;
  }

  for (int kt = 0; kt < HIDDEN / 64; ++kt) {
    __syncthreads();
#pragma unroll
    for (int i = 0; i < 4; ++i) {
      async16(&sA[sx[i]], A + (size_t)(m0 + srow[i]) * HIDDEN + kt * 64 + scol[i]);
      async16(&sB[sx[i]], B + (size_t)(n0 + srow[i]) * HIDDEN + kt * 64 + scol[i]);
    }
    VMCNT0;
    __syncthreads();
#pragma unroll
    for (int kk = 0; kk < 2; ++kk) {
      bf16x8 af[4], bfr[4];
#pragma unroll
      for (int mf = 0; mf < 4; ++mf) {
        int row = wr * 64 + mf * 16 + cc;
        int colb = (kk * 64 + (g << 4)) ^ ((row & 7) << 4);
        af[mf] = *(const bf16x8*)&sA[(row * 128 + colb) >> 1];
      }
#pragma unroll
      for (int nf = 0; nf < 4; ++nf) {
        int row = wc * 64 + nf * 16 + cc;
        int colb = (kk * 64 + (g << 4)) ^ ((row & 7) << 4);
        bfr[nf] = *(const bf16x8*)&sB[(row * 128 + colb) >> 1];
      }
#pragma unroll
      for (int mf = 0; mf < 4; ++mf)
#pragma unroll
        for (int nf = 0; nf < 4; ++nf)
          acc[mf][nf] = __builtin_amdgcn_mfma_f32_16x16x32_bf16(af[mf], bfr[nf], acc[mf][nf], 0, 0, 0);
    }
  }

#pragma unroll
  for (int mf = 0; mf < 4; ++mf) {
#pragma unroll
    for (int nf = 0; nf < 4; ++nf) {
      int n = n0 + wc * 64 + nf * 16 + cc;
      float bval = bias[n];
      int h = n >> 6, d = n & 63;
#pragma unroll
      for (int r = 0; r < 4; ++r) {
        int m = m0 + wr * 64 + mf * 16 + g * 4 + r;
        int b = m >> 10, s = m & 1023;
        out[((((size_t)b * NUM_HEADS + h) * SEQ + s) << 6) + d] = f2bf(acc[mf][nf][r] + bval);
      }
    }
  }
}

// ---------------- merged V GEMM + attention pass 1 (768 blocks, 32 KB LDS, 3/CU) ----------------
// bid<256: V = to @ Wv -> Vt (transpose epilogue). bid>=256: attn1 -> invl.
__global__ __launch_bounds__(256, 3) void k_gemmV_attn1(
    const u16* __restrict__ At, const u16* __restrict__ Wt,
    const float* __restrict__ bv_, u16* __restrict__ Vt,
    const u16* __restrict__ Qh, const u16* __restrict__ Kh,
    const u16* __restrict__ adder, const int* __restrict__ flags,
    float* __restrict__ invl) {
  __shared__ u16 lds[2 * 128 * 64];  // 32 KB, shared by both paths
  int bid = blockIdx.x;
  int tid = threadIdx.x, w = tid >> 6, lane = tid & 63;
  int g = lane >> 4, cc = lane & 15;

  int sx[4], srow7[4], scol7[4];
#pragma unroll
  for (int i = 0; i < 4; ++i) {
    int ch = w * 4 + i;
    int x = ch * 1024 + lane * 16;
    sx[i] = ch * 512;
    int r7 = x >> 7;
    int c7 = (x & 127) ^ ((r7 & 7) << 4);
    srow7[i] = r7; scol7[i] = c7 >> 1;
  }

  if (bid < 256) {
    // ---------------- V GEMM ----------------
    u16* sA = lds;
    u16* sB = lds + 8192;
    const u16* B = Wt + (size_t)2 * HIDDEN * HIDDEN;
    int wg = bid;
    int xcd = wg & 7, j = wg >> 3;
    int ntile = j & 7, mstrip = xcd * 4 + (j >> 3);
    int m0 = mstrip * 128, n0 = ntile * 128;
    int wr = w >> 1, wc = w & 1;
    f32x4 acc[4][4] = {};

    for (int kt = 0; kt < HIDDEN / 64; ++kt) {
      __syncthreads();
#pragma unroll
      for (int i = 0; i < 4; ++i) {
        async16(&sA[sx[i]], At + (size_t)(m0 + srow7[i]) * HIDDEN + kt * 64 + scol7[i]);
        async16(&sB[sx[i]], B + (size_t)(n0 + srow7[i]) * HIDDEN + kt * 64 + scol7[i]);
      }
      VMCNT0;
      __syncthreads();
#pragma unroll
      for (int kk = 0; kk < 2; ++kk) {
        bf16x8 af[4], bfr[4];
#pragma unroll
        for (int mf = 0; mf < 4; ++mf) {
          int row = wr * 64 + mf * 16 + cc;
          int colb = (kk * 64 + (g << 4)) ^ ((row & 7) << 4);
          af[mf] = *(const bf16x8*)&sA[(row * 128 + colb) >> 1];
        }
#pragma unroll
        for (int nf = 0; nf < 4; ++nf) {
          int row = wc * 64 + nf * 16 + cc;
          int colb = (kk * 64 + (g << 4)) ^ ((row & 7) << 4);
          bfr[nf] = *(const bf16x8*)&sB[(row * 128 + colb) >> 1];
        }
#pragma unroll
        for (int mf = 0; mf < 4; ++mf)
#pragma unroll
          for (int nf = 0; nf < 4; ++nf)
            acc[mf][nf] = __builtin_amdgcn_mfma_f32_16x16x32_bf16(af[mf], bfr[nf], acc[mf][nf], 0, 0, 0);
      }
    }

    // V epilogue: transpose via LDS (32 KB), coalesced stores along s
    __syncthreads();
    char* T = (char*)lds;
#pragma unroll
    for (int mf = 0; mf < 4; ++mf) {
#pragma unroll
      for (int nf = 0; nf < 4; ++nf) {
        int nl = wc * 64 + nf * 16 + cc;
        float bval = bv_[n0 + nl];
        int mlb = wr * 64 + mf * 16 + g * 4;
        u16x4 v;
#pragma unroll
        for (int r = 0; r < 4; ++r) v[r] = f2bf(acc[mf][nf][r] + bval);
        int byte = nl * 256 + ((mlb * 2) ^ ((nl & 7) << 4));
        *(u16x4*)(T + byte) = v;
      }
    }
    __syncthreads();
    int nl = tid >> 1, mh = (tid & 1) * 64;
    int b = m0 >> 10, s0 = m0 & 1023;
    u16* dst = &Vt[((size_t)b * 1024 + n0 + nl) * SEQ + s0 + mh];
#pragma unroll
    for (int j2 = 0; j2 < 8; ++j2) {
      int byte = nl * 256 + (((mh + j2 * 8) * 2) ^ ((nl & 7) << 4));
      *(u16x8*)&dst[j2 * 8] = *(const u16x8*)(T + byte);
    }
  } else {
    // ---------------- attn1: row sums -> inv_l ----------------
    u16* sQ = lds;
    u16* sK = lds + 8192;
    int wid = bid - 256;
    int ft = wid & 7, h = (wid >> 3) & 15, b = wid >> 7;
    int f0 = ft * 128;
    int bh = b * NUM_HEADS + h;
    const u16* Qg = Qh + ((size_t)bh * SEQ + f0) * 64;
    const u16* Kg = Kh + (size_t)bh * SEQ * 64;
    const int fbase = w * 32;

    int flgmask = 0;
#pragma unroll
    for (int tt = 0; tt < 8; ++tt)
      flgmask |= (flags[(b * 8 + ft) * 8 + tt] != 0) << tt;

#pragma unroll
    for (int i = 0; i < 4; ++i)
      async16(&sQ[sx[i]], Qg + (size_t)srow7[i] * 64 + scol7[i]);

    float l_run[8];
#pragma unroll
    for (int i = 0; i < 8; ++i) l_run[i] = 0.0f;

    for (int tt = 0; tt < 8; ++tt) {
      __syncthreads();
#pragma unroll
      for (int i = 0; i < 4; ++i)
        async16(&sK[sx[i]], Kg + (size_t)(tt * 128 + srow7[i]) * 64 + scol7[i]);
      VMCNT0;
      __syncthreads();

      f32x4 s[2][8] = {};
#pragma unroll
      for (int kk = 0; kk < 2; ++kk) {
        bf16x8 aq[2], bk8[8];
#pragma unroll
        for (int mf = 0; mf < 2; ++mf) {
          int row = fbase + mf * 16 + cc;
          int colb = (kk * 64 + (g << 4)) ^ ((row & 7) << 4);
          aq[mf] = *(const bf16x8*)&sQ[(row * 128 + colb) >> 1];
        }
#pragma unroll
        for (int nf = 0; nf < 8; ++nf) {
          int row = nf * 16 + cc;
          int colb = (kk * 64 + (g << 4)) ^ ((row & 7) << 4);
          bk8[nf] = *(const bf16x8*)&sK[(row * 128 + colb) >> 1];
        }
#pragma unroll
        for (int mf = 0; mf < 2; ++mf)
#pragma unroll
          for (int nf = 0; nf < 8; ++nf)
            s[mf][nf] = __builtin_amdgcn_mfma_f32_16x16x32_bf16(aq[mf], bk8[nf], s[mf][nf], 0, 0, 0);
      }
#pragma unroll
      for (int mf = 0; mf < 2; ++mf)
#pragma unroll
        for (int nf = 0; nf < 8; ++nf)
          s[mf][nf] = s[mf][nf] * C1;
      if ((flgmask >> tt) & 1) {
        for (int mf = 0; mf < 2; ++mf)
          for (int nf = 0; nf < 8; ++nf)
            for (int r = 0; r < 4; ++r) {
              int frow = f0 + fbase + mf * 16 + g * 4 + r;
              int tcol = tt * 128 + nf * 16 + cc;
              s[mf][nf][r] += bf2f(adder[((size_t)b * SEQ + frow) * SEQ + tcol]);
            }
      }
#pragma unroll
      for (int mf = 0; mf < 2; ++mf)
#pragma unroll
        for (int r = 0; r < 4; ++r) {
          float sum = 0.f;
#pragma unroll
          for (int nf = 0; nf < 8; ++nf) sum += exp2f(s[mf][nf][r]);
          sum += __shfl_xor(sum, 1, 16);
          sum += __shfl_xor(sum, 2, 16);
          sum += __shfl_xor(sum, 4, 16);
          sum += __shfl_xor(sum, 8, 16);
          l_run[mf * 4 + r] += sum;
        }
    }

    if (cc == 0) {
#pragma unroll
      for (int mf = 0; mf < 2; ++mf)
#pragma unroll
        for (int r = 0; r < 4; ++r)
          invl[(size_t)bh * SEQ + f0 + fbase + mf * 16 + g * 4 + r] =
              1.0f / l_run[mf * 4 + r];
    }
  }
}

// ---------------- attention pass 2: recompute S, write probs, accumulate ctx ----------------
__global__ __launch_bounds__(256) void k_attn2(
    const u16* __restrict__ Qh, const u16* __restrict__ Kh, const u16* __restrict__ Vt,
    const u16* __restrict__ adder, const int* __restrict__ flags,
    const float* __restrict__ invl,
    float* __restrict__ ctx, float* __restrict__ probs) {
  __shared__ u16 sQ[128 * 64];   // 16 KB
  __shared__ u16 sK[128 * 64];   // 16 KB
  __shared__ u16 sV[64 * 128];   // 16 KB
  __shared__ u16 sP[128 * 128];  // 32 KB
  int ft = blockIdx.x, h = blockIdx.y, b = blockIdx.z;
  int f0 = ft * 128;
  int bh = b * NUM_HEADS + h;
  const u16* Qg = Qh + ((size_t)bh * SEQ + f0) * 64;
  const u16* Kg = Kh + (size_t)bh * SEQ * 64;
  const u16* Vg = Vt + (size_t)bh * 64 * SEQ;
  int tid = threadIdx.x, w = tid >> 6, lane = tid & 63;
  int g = lane >> 4, cc = lane & 15;
  const int fbase = w * 32;

  int flgmask = 0;
#pragma unroll
  for (int tt = 0; tt < 8; ++tt)
    flgmask |= (flags[(b * 8 + ft) * 8 + tt] != 0) << tt;

  int sx[4], srow7[4], scol7[4], srow8[4], scol8[4];
#pragma unroll
  for (int i = 0; i < 4; ++i) {
    int ch = w * 4 + i;
    int x = ch * 1024 + lane * 16;
    sx[i] = ch * 512;
    int r7 = x >> 7;
    int c7 = (x & 127) ^ ((r7 & 7) << 4);
    srow7[i] = r7; scol7[i] = c7 >> 1;
    int r8 = x >> 8;
    int c8 = (x & 255) ^ ((r8 & 7) << 4);
    srow8[i] = r8; scol8[i] = c8 >> 1;
  }

#pragma unroll
  for (int i = 0; i < 4; ++i)
    async16(&sQ[sx[i]], Qg + (size_t)srow7[i] * 64 + scol7[i]);

  float inv_l[8];
#pragma unroll
  for (int mf = 0; mf < 2; ++mf)
#pragma unroll
    for (int r = 0; r < 4; ++r)
      inv_l[mf * 4 + r] =
          invl[(size_t)bh * SEQ + f0 + fbase + mf * 16 + g * 4 + r];

  f32x4 accO[2][4] = {};

  for (int tt = 0; tt < 8; ++tt) {
    __syncthreads();
#pragma unroll
    for (int i = 0; i < 4; ++i) {
      async16(&sK[sx[i]], Kg + (size_t)(tt * 128 + srow7[i]) * 64 + scol7[i]);
      async16(&sV[sx[i]], Vg + (size_t)srow8[i] * SEQ + tt * 128 + scol8[i]);
    }
    VMCNT0;
    __syncthreads();

    f32x4 s[2][8] = {};
#pragma unroll
    for (int kk = 0; kk < 2; ++kk) {
      bf16x8 aq[2], bk8[8];
#pragma unroll
      for (int mf = 0; mf < 2; ++mf) {
        int row = fbase + mf * 16 + cc;
        int colb = (kk * 64 + (g << 4)) ^ ((row & 7) << 4);
        aq[mf] = *(const bf16x8*)&sQ[(row * 128 + colb) >> 1];
      }
#pragma unroll
      for (int nf = 0; nf < 8; ++nf) {
        int row = nf * 16 + cc;
        int colb = (kk * 64 + (g << 4)) ^ ((row & 7) << 4);
        bk8[nf] = *(const bf16x8*)&sK[(row * 128 + colb) >> 1];
      }
#pragma unroll
      for (int mf = 0; mf < 2; ++mf)
#pragma unroll
        for (int nf = 0; nf < 8; ++nf)
          s[mf][nf] = __builtin_amdgcn_mfma_f32_16x16x32_bf16(aq[mf], bk8[nf], s[mf][nf], 0, 0, 0);
    }
#pragma unroll
    for (int mf = 0; mf < 2; ++mf)
#pragma unroll
      for (int nf = 0; nf < 8; ++nf)
        s[mf][nf] = s[mf][nf] * C1;
    if ((flgmask >> tt) & 1) {
      for (int mf = 0; mf < 2; ++mf)
        for (int nf = 0; nf < 8; ++nf)
          for (int r = 0; r < 4; ++r) {
            int frow = f0 + fbase + mf * 16 + g * 4 + r;
            int tcol = tt * 128 + nf * 16 + cc;
            s[mf][nf][r] += bf2f(adder[((size_t)b * SEQ + frow) * SEQ + tcol]);
          }
    }
#pragma unroll
    for (int mf = 0; mf < 2; ++mf)
#pragma unroll
      for (int nf = 0; nf < 8; ++nf)
#pragma unroll
        for (int r = 0; r < 4; ++r) {
          int idx = mf * 4 + r;
          float p = exp2f(s[mf][nf][r]) * inv_l[idx];
          int frow = fbase + mf * 16 + g * 4 + r;
          int tcol = nf * 16 + cc;
          probs[(((size_t)bh * SEQ) + f0 + frow) * SEQ + tt * 128 + tcol] = p;
          sP[(frow * 256 + ((tcol * 2) ^ ((frow & 7) << 4))) >> 1] = f2bf(p);
        }
#pragma unroll
    for (int ks = 0; ks < 4; ++ks) {
      bf16x8 ap[2], bv8[4];
#pragma unroll
      for (int mf = 0; mf < 2; ++mf) {
        int row = fbase + mf * 16 + cc;
        int colb = (ks * 64 + (g << 4)) ^ ((row & 7) << 4);
        ap[mf] = *(const bf16x8*)&sP[(row * 256 + colb) >> 1];
      }
#pragma unroll
      for (int nf = 0; nf < 4; ++nf) {
        int row = nf * 16 + cc;
        int colb = (ks * 64 + (g << 4)) ^ ((row & 7) << 4);
        bv8[nf] = *(const bf16x8*)&sV[(row * 256 + colb) >> 1];
      }
#pragma unroll
      for (int mf = 0; mf < 2; ++mf)
#pragma unroll
        for (int nf = 0; nf < 4; ++nf)
          accO[mf][nf] = __builtin_amdgcn_mfma_f32_16x16x32_bf16(ap[mf], bv8[nf], accO[mf][nf], 0, 0, 0);
    }
  }

#pragma unroll
  for (int mf = 0; mf < 2; ++mf)
#pragma unroll
    for (int nf = 0; nf < 4; ++nf)
#pragma unroll
      for (int r = 0; r < 4; ++r) {
        int frow = fbase + mf * 16 + g * 4 + r;
        int d = nf * 16 + cc;
        ctx[((size_t)b * SEQ + f0 + frow) * HIDDEN + h * 64 + d] = accO[mf][nf][r];
      }
}

extern "C" void kernel_launch(void* const* d_in, const int* in_sizes, int n_in,
                              void* d_out, int out_size, void* d_ws, size_t ws_size,
                              hipStream_t stream) {
  const float* from = (const float*)d_in[0];
  const float* to   = (const float*)d_in[1];
  const float* mask = (const float*)d_in[2];
  const float* Wq   = (const float*)d_in[3];
  const float* bq   = (const float*)d_in[4];
  const float* Wk   = (const float*)d_in[5];
  const float* bk   = (const float*)d_in[6];
  const float* Wv   = (const float*)d_in[7];
  const float* bv   = (const float*)d_in[8];

  char* ws = (char*)d_ws;
  u16* Af    = (u16*)(ws);
  u16* At    = (u16*)(ws + 8388608);
  u16* Wt    = (u16*)(ws + 16777216);
  u16* adder = (u16*)(ws + 23068672);
  int* flags = (int*)(ws + 31457280);
  u16* Qh    = (u16*)(ws + 31458304);
  u16* Kh    = (u16*)(ws + 39846912);
  u16* Vt    = (u16*)(ws + 48235520);
  float* invl = (float*)(ws);  // reuses Af region (dead after k_gemmQK)

  float* ctx = (float*)d_out;
  float* probs = ctx + (size_t)BATCH * SEQ * HIDDEN;

  k_prep<<<5120, 256, 0, stream>>>(from, Af, to, At, Wq, Wk, Wv, Wt, mask, adder, flags);
  k_gemmQK<<<512, 256, 0, stream>>>(Af, At, Wt, bq, bk, Qh, Kh);
  k_gemmV_attn1<<<768, 256, 0, stream>>>(At, Wt, bv, Vt, Qh, Kh, adder, flags, invl);
  k_attn2<<<dim3(8, 16, 4), 256, 0, stream>>>(Qh, Kh, Vt, adder, flags, invl, ctx, probs);
}